// Round 7
// baseline (520.213 us; speedup 1.0000x reference)
//
#include <hip/hip_runtime.h>
#include <hip/hip_bf16.h>
#include <cstdint>
#include <cstddef>

#define NTOK 8192
#define DMODEL 1024
#define DFF 4096
#define NEXP 8
#define CAP 2048

typedef __attribute__((ext_vector_type(8))) __bf16 bf16x8;
typedef __attribute__((ext_vector_type(4))) float f32x4;

__device__ __forceinline__ void gload16(const void* g, void* l) {
  __builtin_amdgcn_global_load_lds(
      (__attribute__((address_space(1))) void*)(g),
      (__attribute__((address_space(3))) void*)(l),
      16, 0, 0);
}
#define VMWAIT_(n) asm volatile("s_waitcnt vmcnt(" #n ")" ::: "memory")
#define VMWAIT(n) VMWAIT_(n)
#define MEMFENCE asm volatile("" ::: "memory")
#define LGKM0                                                                  \
  asm volatile("s_waitcnt lgkmcnt(0)" ::: "memory");                           \
  __builtin_amdgcn_sched_barrier(0);

__global__ __launch_bounds__(256) void zero_f32(float* p, int n4) {
  int i = blockIdx.x * blockDim.x + threadIdx.x;
  int stride = gridDim.x * blockDim.x;
  float4 z = make_float4(0.f, 0.f, 0.f, 0.f);
  for (; i < n4; i += stride) ((float4*)p)[i] = z;
}

__global__ __launch_bounds__(256) void router_kernel(
    const float* __restrict__ x, const float* __restrict__ Wr,
    float* __restrict__ scoresT, __hip_bfloat16* __restrict__ xb) {
  const int lane = threadIdx.x & 63;
  const int t = blockIdx.x * 4 + (threadIdx.x >> 6);
  const float* xr = x + (size_t)t * DMODEL;
  float acc[NEXP];
#pragma unroll
  for (int j = 0; j < NEXP; ++j) acc[j] = 0.f;
#pragma unroll
  for (int it = 0; it < DMODEL / 64; ++it) {
    int d = it * 64 + lane;
    float xv = xr[d];
    xb[(size_t)t * DMODEL + d] = __float2bfloat16(xv);
    const float4* w = (const float4*)(Wr + (size_t)d * NEXP);
    float4 w0 = w[0], w1 = w[1];
    acc[0] += xv * w0.x; acc[1] += xv * w0.y; acc[2] += xv * w0.z; acc[3] += xv * w0.w;
    acc[4] += xv * w1.x; acc[5] += xv * w1.y; acc[6] += xv * w1.z; acc[7] += xv * w1.w;
  }
#pragma unroll
  for (int off = 32; off; off >>= 1) {
#pragma unroll
    for (int j = 0; j < NEXP; ++j) acc[j] += __shfl_xor(acc[j], off);
  }
  float m = acc[0];
#pragma unroll
  for (int j = 1; j < NEXP; ++j) m = fmaxf(m, acc[j]);
  float s = 0.f;
#pragma unroll
  for (int j = 0; j < NEXP; ++j) { acc[j] = expf(acc[j] - m); s += acc[j]; }
  float inv = 1.f / s;
  if (lane < NEXP) scoresT[(size_t)lane * NTOK + t] = acc[lane] * inv;
}

__global__ __launch_bounds__(256) void topk_kernel(
    const float* __restrict__ scoresT, float* __restrict__ G, int* __restrict__ IDX) {
  __shared__ uint32_t sb[NTOK];
  __shared__ uint32_t hist[256];
  __shared__ uint32_t s_prefix, s_rem;
  __shared__ uint32_t eq_list[256];
  __shared__ uint32_t eq_cnt, gt_cnt;
  const int e = blockIdx.x, tid = threadIdx.x;
  const float* se = scoresT + (size_t)e * NTOK;
  for (int i = tid; i < NTOK; i += 256) sb[i] = __float_as_uint(se[i]);
  if (tid == 0) { s_prefix = 0u; s_rem = CAP; eq_cnt = 0u; gt_cnt = 0u; }
  __syncthreads();
  for (int r = 0; r < 4; ++r) {
    const int shift = 24 - 8 * r;
    for (int i = tid; i < 256; i += 256) hist[i] = 0u;
    __syncthreads();
    uint32_t pfx = s_prefix;
    for (int i = tid; i < NTOK; i += 256) {
      uint32_t b = sb[i];
      if (((b >> shift) >> 8) == pfx) atomicAdd(&hist[(b >> shift) & 255u], 1u);
    }
    __syncthreads();
    if (tid == 0) {
      uint32_t rem = s_rem, cum = 0u;
      int d = 255;
      for (; d > 0; --d) {
        if (cum + hist[d] >= rem) break;
        cum += hist[d];
      }
      s_prefix = (pfx << 8) | (uint32_t)d;
      s_rem = rem - cum;
    }
    __syncthreads();
  }
  const uint32_t T = s_prefix, need = s_rem;
  for (int i = tid; i < NTOK; i += 256) {
    uint32_t b = sb[i];
    if (b > T) {
      uint32_t p = atomicAdd(&gt_cnt, 1u);
      IDX[(size_t)e * CAP + p] = i;
      G[(size_t)e * CAP + p] = __uint_as_float(b);
    } else if (b == T) {
      uint32_t c = atomicAdd(&eq_cnt, 1u);
      if (c < 256u) eq_list[c] = (uint32_t)i;
    }
  }
  __syncthreads();
  if (tid == 0) {
    uint32_t base = gt_cnt;
    uint32_t c = eq_cnt < 256u ? eq_cnt : 256u;
    for (uint32_t s = 0; s < need; ++s) {
      uint32_t mv = 0xFFFFFFFFu; int mi = 0;
      for (uint32_t j = 0; j < c; ++j)
        if (eq_list[j] < mv) { mv = eq_list[j]; mi = (int)j; }
      eq_list[mi] = 0xFFFFFFFFu;
      IDX[(size_t)e * CAP + base + s] = (int)mv;
      G[(size_t)e * CAP + base + s] = __uint_as_float(T);
    }
  }
}

__global__ __launch_bounds__(256) void transpose_cvt(
    const float* __restrict__ in, __hip_bfloat16* __restrict__ out, int R, int C) {
  __shared__ float tile[32][33];
  const int e = blockIdx.z;
  const float* ine = in + (size_t)e * R * C;
  __hip_bfloat16* oute = out + (size_t)e * R * C;
  const int c0 = blockIdx.x * 32, r0 = blockIdx.y * 32;
  const int tx = threadIdx.x, ty = threadIdx.y;
#pragma unroll
  for (int i = 0; i < 4; ++i)
    tile[ty + i * 8][tx] = ine[(size_t)(r0 + ty + i * 8) * C + (c0 + tx)];
  __syncthreads();
#pragma unroll
  for (int i = 0; i < 4; ++i)
    oute[(size_t)(c0 + ty + i * 8) * R + (r0 + tx)] =
        __float2bfloat16(tile[tx][ty + i * 8]);
}

// ===== 128x256 tile, BK=32, ring-3 LDS, reg-double-buffered fragments ======
// LDS 3 slots x 24 KB (A 8 KB [128r x 32k] + B 16 KB [256r x 32k]) = 72 KB
// -> 2 blocks/CU. 4 waves (2M x 2N), wave tile 64x128, acc[4][8].
// Slot row r: logical 16B k-slot s stored at phys (s+r)&3; global source
// inverse-rotated (G21). Per kt: ONE barrier, counted vmcnt(6) (stage issued
// 3 tiles ahead), lgkm(0) amortized (covers reads issued LAST kt, after a
// full 32-MFMA cluster). ds_read-issue -> MFMA has NO intervening wait:
// 12 reads of kt+1 overlap the 32 MFMA of kt. AITER-style: never drain.

#define RDSET(BUF, AV, BV)                                                     \
  {                                                                            \
    _Pragma("unroll") for (int mi = 0; mi < 4; ++mi) AV[mi] =                  \
        *(const bf16x8*)((BUF) + offA[mi]);                                    \
    _Pragma("unroll") for (int ni = 0; ni < 8; ++ni) BV[ni] =                  \
        *(const bf16x8*)((BUF) + offB[ni]);                                    \
  }
#define STAGE6(BUF)                                                            \
  {                                                                            \
    _Pragma("unroll") for (int i = 0; i < 2; ++i) {                            \
      gload16(pa[i], (BUF) + (i * 256 + tid) * 16);                            \
      pa[i] += 64;                                                             \
    }                                                                          \
    _Pragma("unroll") for (int i = 0; i < 4; ++i) {                            \
      gload16(pb[i], (BUF) + 8192 + (i * 256 + tid) * 16);                     \
      pb[i] += 64;                                                             \
    }                                                                          \
  }
#define MFMA_SET(AV, BV)                                                       \
  {                                                                            \
    __builtin_amdgcn_s_setprio(1);                                             \
    _Pragma("unroll") for (int mi = 0; mi < 4; ++mi)                           \
        _Pragma("unroll") for (int ni = 0; ni < 8; ++ni) acc[mi][ni] =         \
        __builtin_amdgcn_mfma_f32_16x16x32_bf16(AV[mi], BV[ni], acc[mi][ni],   \
                                                0, 0, 0);                      \
    __builtin_amdgcn_s_setprio(0);                                             \
  }
#define ROTATE                                                                 \
  { char* t_ = bufC; bufC = bufN; bufN = bufW; bufW = t_; }
#define BODY_FULL(AVc, BVc, AVr, BVr)                                          \
  LGKM0; VMWAIT(6);                                                            \
  __builtin_amdgcn_s_barrier(); MEMFENCE;                                      \
  STAGE6(bufC);                                                                \
  RDSET(bufN, AVr, BVr);                                                       \
  MFMA_SET(AVc, BVc);                                                          \
  ROTATE
#define BODY_NOSTAGE(AVc, BVc, AVr, BVr)                                       \
  LGKM0; VMWAIT(6);                                                            \
  __builtin_amdgcn_s_barrier(); MEMFENCE;                                      \
  RDSET(bufN, AVr, BVr);                                                       \
  MFMA_SET(AVc, BVc);                                                          \
  ROTATE
#define BODY_VM0(AVc, BVc, AVr, BVr)                                           \
  LGKM0; VMWAIT(0);                                                            \
  __builtin_amdgcn_s_barrier(); MEMFENCE;                                      \
  RDSET(bufN, AVr, BVr);                                                       \
  MFMA_SET(AVc, BVc);                                                          \
  ROTATE

template <int NKT>
__device__ __forceinline__ void gemm_core7(
    const char* pa0, const char* pa1,
    const char* pb0, const char* pb1, const char* pb2, const char* pb3,
    char* smem, f32x4 (&acc)[4][8]) {
  const int tid = threadIdx.x;
  const int wave = tid >> 6, lane = tid & 63;
  const int wm = wave >> 1, wn = wave & 1;
  const int lrow = lane & 15, lgrp = lane >> 4;

  const char* pa[2] = {pa0, pa1};
  const char* pb[4] = {pb0, pb1, pb2, pb3};

  int offA[4], offB[8];
#pragma unroll
  for (int mi = 0; mi < 4; ++mi) {
    int rL = wm * 64 + mi * 16 + lrow;
    offA[mi] = rL * 64 + (((lgrp + rL) & 3) << 4);
  }
#pragma unroll
  for (int ni = 0; ni < 8; ++ni) {
    int rL = wn * 128 + ni * 16 + lrow;
    offB[ni] = 8192 + rL * 64 + (((lgrp + rL) & 3) << 4);
  }

  char* bufC = smem;
  char* bufN = smem + 24576;
  char* bufW = smem + 49152;

  bf16x8 avA[4], bvA[8], avB[4], bvB[8];

  // prologue: stage kt0,kt1,kt2 into the 3 slots; wait kt0; read kt0 frags
  STAGE6(bufC);
  STAGE6(bufN);
  STAGE6(bufW);
  VMWAIT(12);
  __builtin_amdgcn_s_barrier();
  MEMFENCE;
  RDSET(bufC, avA, bvA);

#pragma unroll 1
  for (int t = 0; t < (NKT - 4) / 2; ++t) {
    BODY_FULL(avA, bvA, avB, bvB);   // even kt: consume A, read B, stage kt+3
    BODY_FULL(avB, bvB, avA, bvA);   // odd  kt
  }
  BODY_FULL(avA, bvA, avB, bvB);     // kt = NKT-4 (stages kt = NKT-1)
  BODY_NOSTAGE(avB, bvB, avA, bvA);  // kt = NKT-3
  BODY_VM0(avA, bvA, avB, bvB);      // kt = NKT-2
  LGKM0;                             // kt = NKT-1
  MFMA_SET(avB, bvB);
}

__device__ __forceinline__ float gelu_tanh(float v) {
  float t = 0.7978845608028654f * (v + 0.044715f * v * v * v);
  float e = __expf(2.f * t);
  float th = 1.f - 2.f / (e + 1.f);
  return 0.5f * v * (1.f + th);
}

__global__ __launch_bounds__(256, 2) void gemm1_kernel(
    const __hip_bfloat16* __restrict__ xb,
    const __hip_bfloat16* __restrict__ W1t,
    const float* __restrict__ b1,
    const int* __restrict__ IDX,
    __hip_bfloat16* __restrict__ h, int e0, int nblk) {
  __shared__ __align__(16) char smem[73728];
  int lin = blockIdx.x;
  { int q = nblk >> 3; lin = (lin & 7) * q + (lin >> 3); }  // XCD-contiguous
  const int tm = lin & 15, tn = (lin >> 4) & 15, ez = lin >> 8;
  const int e = e0 + ez;
  const int tid = threadIdx.x, wave = tid >> 6, lane = tid & 63;
  const int wm = wave >> 1, wn = wave & 1;
  const int lrow = lane & 15, lgrp = lane >> 4;

  const char* pa[2];
  const char* pb[4];
#pragma unroll
  for (int i = 0; i < 2; ++i) {
    int u = i * 256 + tid, r = u >> 2, s = ((u & 3) - r) & 3;
    int tok = IDX[e * CAP + tm * 128 + r];
    pa[i] = (const char*)(xb + (size_t)tok * DMODEL) + s * 16;
  }
#pragma unroll
  for (int i = 0; i < 4; ++i) {
    int u = i * 256 + tid, r = u >> 2, s = ((u & 3) - r) & 3;
    pb[i] = (const char*)(W1t + ((size_t)e * DFF + tn * 256 + r) * DMODEL) + s * 16;
  }

  f32x4 acc[4][8];
  f32x4 zero = {0.f, 0.f, 0.f, 0.f};
#pragma unroll
  for (int mi = 0; mi < 4; ++mi)
#pragma unroll
    for (int ni = 0; ni < 8; ++ni) acc[mi][ni] = zero;

  gemm_core7<DMODEL / 32>(pa[0], pa[1], pb[0], pb[1], pb[2], pb[3], smem, acc);

  __hip_bfloat16* he = h + (size_t)ez * CAP * DFF;
  const float* b1e = b1 + (size_t)e * DFF;
  float bvals[8];
#pragma unroll
  for (int ni = 0; ni < 8; ++ni)
    bvals[ni] = b1e[tn * 256 + wn * 128 + ni * 16 + lrow];
#pragma unroll
  for (int mi = 0; mi < 4; ++mi) {
#pragma unroll
    for (int j = 0; j < 4; ++j) {
      int row = tm * 128 + wm * 64 + mi * 16 + lgrp * 4 + j;
      __hip_bfloat16* hrow = he + (size_t)row * DFF;
#pragma unroll
      for (int ni = 0; ni < 8; ++ni) {
        int col = tn * 256 + wn * 128 + ni * 16 + lrow;
        float v = acc[mi][ni][j] + bvals[ni];
        hrow[col] = __float2bfloat16(gelu_tanh(v));
      }
    }
  }
}

__global__ __launch_bounds__(256, 2) void gemm2_kernel(
    const __hip_bfloat16* __restrict__ h,
    const __hip_bfloat16* __restrict__ W2t,
    const float* __restrict__ b2,
    const int* __restrict__ IDX, const float* __restrict__ G,
    float* __restrict__ out, int e0, int nblk) {
  __shared__ __align__(16) char smem[73728];
  int lin = blockIdx.x;
  { int q = nblk >> 3; lin = (lin & 7) * q + (lin >> 3); }
  const int tm = lin & 15, tn = (lin >> 4) & 3, ez = lin >> 6;
  const int e = e0 + ez;
  const int tid = threadIdx.x, wave = tid >> 6, lane = tid & 63;
  const int wm = wave >> 1, wn = wave & 1;
  const int lrow = lane & 15, lgrp = lane >> 4;

  const char* pa[2];
  const char* pb[4];
#pragma unroll
  for (int i = 0; i < 2; ++i) {
    int u = i * 256 + tid, r = u >> 2, s = ((u & 3) - r) & 3;
    pa[i] = (const char*)(h + ((size_t)ez * CAP + tm * 128 + r) * DFF) + s * 16;
  }
#pragma unroll
  for (int i = 0; i < 4; ++i) {
    int u = i * 256 + tid, r = u >> 2, s = ((u & 3) - r) & 3;
    pb[i] = (const char*)(W2t + ((size_t)e * DMODEL + tn * 256 + r) * DFF) + s * 16;
  }

  f32x4 acc[4][8];
  f32x4 zero = {0.f, 0.f, 0.f, 0.f};
#pragma unroll
  for (int mi = 0; mi < 4; ++mi)
#pragma unroll
    for (int ni = 0; ni < 8; ++ni) acc[mi][ni] = zero;

  gemm_core7<DFF / 32>(pa[0], pa[1], pb[0], pb[1], pb[2], pb[3], smem, acc);

  const float* b2e = b2 + (size_t)e * DMODEL;
  const int* idxe = IDX + (size_t)e * CAP;
  const float* ge = G + (size_t)e * CAP;
  float bvals[8];
#pragma unroll
  for (int ni = 0; ni < 8; ++ni)
    bvals[ni] = b2e[tn * 256 + wn * 128 + ni * 16 + lrow];
#pragma unroll
  for (int mi = 0; mi < 4; ++mi) {
#pragma unroll
    for (int j = 0; j < 4; ++j) {
      int row = tm * 128 + wm * 64 + mi * 16 + lgrp * 4 + j;
      float g = ge[row];
      int tok = idxe[row];
      float* orow = out + (size_t)tok * DMODEL;
#pragma unroll
      for (int ni = 0; ni < 8; ++ni) {
        int col = tn * 256 + wn * 128 + ni * 16 + lrow;
        atomicAdd(orow + col, (acc[mi][ni][j] + bvals[ni]) * g);
      }
    }
  }
}

extern "C" void kernel_launch(void* const* d_in, const int* in_sizes, int n_in,
                              void* d_out, int out_size, void* d_ws, size_t ws_size,
                              hipStream_t stream) {
  const float* x  = (const float*)d_in[0];
  const float* Wr = (const float*)d_in[1];
  const float* W1 = (const float*)d_in[2];
  const float* b1 = (const float*)d_in[3];
  const float* W2 = (const float*)d_in[4];
  const float* b2 = (const float*)d_in[5];
  float* out = (float*)d_out;
  char* ws = (char*)d_ws;

  size_t off = 0;
  float* scoresT = (float*)(ws + off); off += (size_t)NEXP * NTOK * 4;
  float* G       = (float*)(ws + off); off += (size_t)NEXP * CAP * 4;
  int*   IDX     = (int*)(ws + off);   off += (size_t)NEXP * CAP * 4;
  __hip_bfloat16* xb  = (__hip_bfloat16*)(ws + off); off += (size_t)NTOK * DMODEL * 2;
  __hip_bfloat16* W1t = (__hip_bfloat16*)(ws + off); off += (size_t)NEXP * DFF * DMODEL * 2;
  __hip_bfloat16* W2t = (__hip_bfloat16*)(ws + off); off += (size_t)NEXP * DMODEL * DFF * 2;
  __hip_bfloat16* hbuf = (__hip_bfloat16*)(ws + off);
  size_t h_per_e = (size_t)CAP * DFF * 2;
  size_t avail = (ws_size > off) ? (ws_size - off) : 0;
  int EC = (int)(avail / h_per_e);
  if (EC < 1) EC = 1;
  if (EC > NEXP) EC = NEXP;

  zero_f32<<<512, 256, 0, stream>>>(out, out_size / 4);
  router_kernel<<<NTOK / 4, 256, 0, stream>>>(x, Wr, scoresT, xb);
  topk_kernel<<<NEXP, 256, 0, stream>>>(scoresT, G, IDX);
  transpose_cvt<<<dim3(DFF / 32, DMODEL / 32, NEXP), dim3(32, 8), 0, stream>>>(
      W1, W1t, DMODEL, DFF);
  transpose_cvt<<<dim3(DMODEL / 32, DFF / 32, NEXP), dim3(32, 8), 0, stream>>>(
      W2, W2t, DFF, DMODEL);
  for (int e0 = 0; e0 < NEXP; e0 += EC) {
    int ne = (NEXP - e0 < EC) ? (NEXP - e0) : EC;
    int nblk1 = 256 * ne;   // 16 tm x 16 tn per expert
    gemm1_kernel<<<nblk1, 256, 0, stream>>>(xb, W1t, b1, IDX, hbuf, e0, nblk1);
    int nblk2 = 64 * ne;    // 16 tm x 4 tn per expert
    gemm2_kernel<<<nblk2, 256, 0, stream>>>(hbuf, W2t, b2, IDX, G, out, e0, nblk2);
  }
}

// Round 8
// 475.360 us; speedup vs baseline: 1.0944x; 1.0944x over previous
//
#include <hip/hip_runtime.h>
#include <hip/hip_bf16.h>
#include <cstdint>
#include <cstddef>

#define NTOK 8192
#define DMODEL 1024
#define DFF 4096
#define NEXP 8
#define CAP 2048

typedef __attribute__((ext_vector_type(8))) __bf16 bf16x8;
typedef __attribute__((ext_vector_type(4))) float f32x4;

__device__ __forceinline__ void gload16(const void* g, void* l) {
  __builtin_amdgcn_global_load_lds(
      (__attribute__((address_space(1))) void*)(g),
      (__attribute__((address_space(3))) void*)(l),
      16, 0, 0);
}
#define VMWAIT_(n) asm volatile("s_waitcnt vmcnt(" #n ")" ::: "memory")
#define VMWAIT(n) VMWAIT_(n)
#define MEMFENCE asm volatile("" ::: "memory")

__global__ __launch_bounds__(256) void zero_f32(float* p, int n4) {
  int i = blockIdx.x * blockDim.x + threadIdx.x;
  int stride = gridDim.x * blockDim.x;
  float4 z = make_float4(0.f, 0.f, 0.f, 0.f);
  for (; i < n4; i += stride) ((float4*)p)[i] = z;
}

__global__ __launch_bounds__(256) void router_kernel(
    const float* __restrict__ x, const float* __restrict__ Wr,
    float* __restrict__ scoresT, __hip_bfloat16* __restrict__ xb) {
  const int lane = threadIdx.x & 63;
  const int t = blockIdx.x * 4 + (threadIdx.x >> 6);
  const float* xr = x + (size_t)t * DMODEL;
  float acc[NEXP];
#pragma unroll
  for (int j = 0; j < NEXP; ++j) acc[j] = 0.f;
#pragma unroll
  for (int it = 0; it < DMODEL / 64; ++it) {
    int d = it * 64 + lane;
    float xv = xr[d];
    xb[(size_t)t * DMODEL + d] = __float2bfloat16(xv);
    const float4* w = (const float4*)(Wr + (size_t)d * NEXP);
    float4 w0 = w[0], w1 = w[1];
    acc[0] += xv * w0.x; acc[1] += xv * w0.y; acc[2] += xv * w0.z; acc[3] += xv * w0.w;
    acc[4] += xv * w1.x; acc[5] += xv * w1.y; acc[6] += xv * w1.z; acc[7] += xv * w1.w;
  }
#pragma unroll
  for (int off = 32; off; off >>= 1) {
#pragma unroll
    for (int j = 0; j < NEXP; ++j) acc[j] += __shfl_xor(acc[j], off);
  }
  float m = acc[0];
#pragma unroll
  for (int j = 1; j < NEXP; ++j) m = fmaxf(m, acc[j]);
  float s = 0.f;
#pragma unroll
  for (int j = 0; j < NEXP; ++j) { acc[j] = expf(acc[j] - m); s += acc[j]; }
  float inv = 1.f / s;
  if (lane < NEXP) scoresT[(size_t)lane * NTOK + t] = acc[lane] * inv;
}

__global__ __launch_bounds__(256) void topk_kernel(
    const float* __restrict__ scoresT, float* __restrict__ G, int* __restrict__ IDX) {
  __shared__ uint32_t sb[NTOK];
  __shared__ uint32_t hist[256];
  __shared__ uint32_t s_prefix, s_rem;
  __shared__ uint32_t eq_list[256];
  __shared__ uint32_t eq_cnt, gt_cnt;
  const int e = blockIdx.x, tid = threadIdx.x;
  const float* se = scoresT + (size_t)e * NTOK;
  for (int i = tid; i < NTOK; i += 256) sb[i] = __float_as_uint(se[i]);
  if (tid == 0) { s_prefix = 0u; s_rem = CAP; eq_cnt = 0u; gt_cnt = 0u; }
  __syncthreads();
  for (int r = 0; r < 4; ++r) {
    const int shift = 24 - 8 * r;
    for (int i = tid; i < 256; i += 256) hist[i] = 0u;
    __syncthreads();
    uint32_t pfx = s_prefix;
    for (int i = tid; i < NTOK; i += 256) {
      uint32_t b = sb[i];
      if (((b >> shift) >> 8) == pfx) atomicAdd(&hist[(b >> shift) & 255u], 1u);
    }
    __syncthreads();
    if (tid == 0) {
      uint32_t rem = s_rem, cum = 0u;
      int d = 255;
      for (; d > 0; --d) {
        if (cum + hist[d] >= rem) break;
        cum += hist[d];
      }
      s_prefix = (pfx << 8) | (uint32_t)d;
      s_rem = rem - cum;
    }
    __syncthreads();
  }
  const uint32_t T = s_prefix, need = s_rem;
  for (int i = tid; i < NTOK; i += 256) {
    uint32_t b = sb[i];
    if (b > T) {
      uint32_t p = atomicAdd(&gt_cnt, 1u);
      IDX[(size_t)e * CAP + p] = i;
      G[(size_t)e * CAP + p] = __uint_as_float(b);
    } else if (b == T) {
      uint32_t c = atomicAdd(&eq_cnt, 1u);
      if (c < 256u) eq_list[c] = (uint32_t)i;
    }
  }
  __syncthreads();
  if (tid == 0) {
    uint32_t base = gt_cnt;
    uint32_t c = eq_cnt < 256u ? eq_cnt : 256u;
    for (uint32_t s = 0; s < need; ++s) {
      uint32_t mv = 0xFFFFFFFFu; int mi = 0;
      for (uint32_t j = 0; j < c; ++j)
        if (eq_list[j] < mv) { mv = eq_list[j]; mi = (int)j; }
      eq_list[mi] = 0xFFFFFFFFu;
      IDX[(size_t)e * CAP + base + s] = (int)mv;
      G[(size_t)e * CAP + base + s] = __uint_as_float(T);
    }
  }
}

__global__ __launch_bounds__(256) void transpose_cvt(
    const float* __restrict__ in, __hip_bfloat16* __restrict__ out, int R, int C) {
  __shared__ float tile[32][33];
  const int e = blockIdx.z;
  const float* ine = in + (size_t)e * R * C;
  __hip_bfloat16* oute = out + (size_t)e * R * C;
  const int c0 = blockIdx.x * 32, r0 = blockIdx.y * 32;
  const int tx = threadIdx.x, ty = threadIdx.y;
#pragma unroll
  for (int i = 0; i < 4; ++i)
    tile[ty + i * 8][tx] = ine[(size_t)(r0 + ty + i * 8) * C + (c0 + tx)];
  __syncthreads();
  const int rp = (tx & 15) * 2;
#pragma unroll
  for (int i = 0; i < 2; ++i) {
    int cl = ty + (tx >> 4) * 8 + i * 16;
    __hip_bfloat16 a = __float2bfloat16(tile[rp][cl]);
    __hip_bfloat16 b = __float2bfloat16(tile[rp + 1][cl]);
    ushort2 v = make_ushort2(*(unsigned short*)&a, *(unsigned short*)&b);
    *(ushort2*)(&oute[(size_t)(c0 + cl) * R + (r0 + rp)]) = v;
  }
}

// ===== 256x256, BK=64, 8-phase / 2-K-tile pipeline (leading barriers only) ==
// LDS 128 KiB: buf d at d*65536: A halves h*16384, B at +32768+h*16384.
// Half = 128 rows x 64 k (16 KB). Row rL: logical 16B slot s at phys (s+rL)&7;
// global source inverse-rotated (G21). Per phase: quadrant ds_reads; stage ONE
// half; BAR; lgkm(0)+sched_barrier; setprio(1); 16 MFMA; setprio(0).
// Trailing barriers removed (proven redundant: phase-N reads are lgkm-drained
// before BAR(N+1); phase-N+2 stage issuers have passed BAR(N+1)) -> waves slip
// one phase: reads/stages of N+1 overlap MFMA of N. vmcnt(4)+BAR only at
// ph4/ph8 (FIFO: completes prior-iter B-halves + this-iter A-halves exactly).

#define RD_A(BASE, H)                                                          \
  {                                                                            \
    _Pragma("unroll") for (int mi = 0; mi < 4; ++mi)                           \
        _Pragma("unroll") for (int ks = 0; ks < 2; ++ks) av[mi][ks] =          \
        *(const bf16x8*)((BASE) + Ab + offA[(H)*4 + mi][ks]);                  \
  }
#define RD_B(BASE, BV, H2)                                                     \
  {                                                                            \
    _Pragma("unroll") for (int ni = 0; ni < 2; ++ni)                           \
        _Pragma("unroll") for (int ks = 0; ks < 2; ++ks) BV[ni][ks] =          \
        *(const bf16x8*)((BASE) + Bb + offB[(H2)*2 + ni][ks]);                 \
  }
#define STAGE_A(H, BUF)                                                        \
  {                                                                            \
    gload16(pa[(H)*2], (BUF) + (H)*16384 + dst);                               \
    pa[(H)*2] += 128;                                                          \
    gload16(pa[(H)*2 + 1], (BUF) + (H)*16384 + 8192 + dst);                    \
    pa[(H)*2 + 1] += 128;                                                      \
  }
#define STAGE_B(H, BUF)                                                        \
  {                                                                            \
    gload16(pb[(H)*2], (BUF) + 32768 + (H)*16384 + dst);                       \
    pb[(H)*2] += 128;                                                          \
    gload16(pb[(H)*2 + 1], (BUF) + 32768 + (H)*16384 + 8192 + dst);            \
    pb[(H)*2 + 1] += 128;                                                      \
  }
#define PH_PRE                                                                 \
  __builtin_amdgcn_s_barrier();                                                \
  MEMFENCE;                                                                    \
  asm volatile("s_waitcnt lgkmcnt(0)" ::: "memory");                           \
  __builtin_amdgcn_sched_barrier(0);                                           \
  __builtin_amdgcn_s_setprio(1);
#define PH_POST __builtin_amdgcn_s_setprio(0);
#define MFMA_Q(MB, NB, BV)                                                     \
  {                                                                            \
    _Pragma("unroll") for (int mi = 0; mi < 4; ++mi)                           \
        _Pragma("unroll") for (int ni = 0; ni < 2; ++ni)                       \
            _Pragma("unroll") for (int ks = 0; ks < 2; ++ks)                   \
                acc[(MB) + mi][(NB) + ni] =                                    \
        __builtin_amdgcn_mfma_f32_16x16x32_bf16(                               \
            av[mi][ks], BV[ni][ks], acc[(MB) + mi][(NB) + ni], 0, 0, 0);       \
  }

template <int NKT>
__device__ __forceinline__ void gemm_core8(
    const char* pa0, const char* pa1, const char* pa2, const char* pa3,
    const char* pb0, const char* pb1, const char* pb2, const char* pb3,
    char* smem, f32x4 (&acc)[8][4]) {
  const int tid = threadIdx.x;
  const int wave = tid >> 6, lane = tid & 63;
  const int wm = wave >> 2, wn = wave & 3;
  const int lrow = lane & 15, lgrp = lane >> 4;
  const int dst = tid * 16;

  const char* pa[4] = {pa0, pa1, pa2, pa3};
  const char* pb[4] = {pb0, pb1, pb2, pb3};

  int offA[8][2], offB[4][2];
#pragma unroll
  for (int mi = 0; mi < 8; ++mi) {
    int rL = mi * 16 + lrow;
#pragma unroll
    for (int ks = 0; ks < 2; ++ks)
      offA[mi][ks] = rL * 128 + ((((ks * 4 + lgrp) + rL) & 7) << 4);
  }
#pragma unroll
  for (int ni = 0; ni < 4; ++ni) {
    int rL = (wn & 1) * 64 + ni * 16 + lrow;
#pragma unroll
    for (int ks = 0; ks < 2; ++ks)
      offB[ni][ks] = rL * 128 + ((((ks * 4 + lgrp) + rL) & 7) << 4);
  }
  const int Ab = wm * 16384;
  const int Bb = 32768 + (wn >> 1) * 16384;

  char* b0 = smem;
  char* b1 = smem + 65536;

  // prologue: buf0 <- kt0 (A h0,h1 + B h0,h1), buf1 <- kt1 B halves
#pragma unroll
  for (int g = 0; g < 4; ++g) {
    gload16(pa[g], b0 + (g >> 1) * 16384 + (g & 1) * 8192 + dst);
    pa[g] += 128;
  }
#pragma unroll
  for (int g = 0; g < 4; ++g) {
    gload16(pb[g], b0 + 32768 + (g >> 1) * 16384 + (g & 1) * 8192 + dst);
    pb[g] += 128;
  }
#pragma unroll
  for (int g = 0; g < 4; ++g) {
    gload16(pb[g], b1 + 32768 + (g >> 1) * 16384 + (g & 1) * 8192 + dst);
    pb[g] += 128;
  }
  VMWAIT(4);
  __builtin_amdgcn_s_barrier();
  MEMFENCE;

  bf16x8 av[4][2], bv0[2][2], bv1[2][2];

  for (int i = 0; i < NKT / 2; ++i) {
    const bool st2 = (2 * i + 2 < NKT);
    const bool st3 = (2 * i + 3 < NKT);

    // ---- phase 1: q(m0,n0) of kt0
    RD_A(b0, 0); RD_B(b0, bv0, 0);
    STAGE_A(0, b1);
    PH_PRE; MFMA_Q(0, 0, bv0); PH_POST;
    // ---- phase 2: q(m0,n1)
    RD_B(b0, bv1, 1);
    STAGE_A(1, b1);
    PH_PRE; MFMA_Q(0, 2, bv1); PH_POST;
    // ---- phase 3: q(m1,n1)
    RD_A(b0, 1);
    if (st2) STAGE_B(0, b0);
    PH_PRE; MFMA_Q(4, 2, bv1); PH_POST;
    // ---- phase 4: q(m1,n0)  [gate for kt1 reads]
    if (st2) STAGE_B(1, b0);
    PH_PRE; MFMA_Q(4, 0, bv0);
    __builtin_amdgcn_s_setprio(0);
    if (st2) { VMWAIT(4); } else { VMWAIT(0); }
    __builtin_amdgcn_s_barrier();
    MEMFENCE;

    // ---- phase 5: q(m0,n0) of kt1
    RD_A(b1, 0); RD_B(b1, bv0, 0);
    if (st2) STAGE_A(0, b0);
    PH_PRE; MFMA_Q(0, 0, bv0); PH_POST;
    // ---- phase 6: q(m0,n1)
    RD_B(b1, bv1, 1);
    if (st2) STAGE_A(1, b0);
    PH_PRE; MFMA_Q(0, 2, bv1); PH_POST;
    // ---- phase 7: q(m1,n1)
    RD_A(b1, 1);
    if (st3) STAGE_B(0, b1);
    PH_PRE; MFMA_Q(4, 2, bv1); PH_POST;
    // ---- phase 8: q(m1,n0)  [gate for next-iter kt0 reads]
    if (st3) STAGE_B(1, b1);
    PH_PRE; MFMA_Q(4, 0, bv0);
    __builtin_amdgcn_s_setprio(0);
    if (st3) { VMWAIT(4); }
    __builtin_amdgcn_s_barrier();
    MEMFENCE;
  }
}

__device__ __forceinline__ float gelu_tanh(float v) {
  float t = 0.7978845608028654f * (v + 0.044715f * v * v * v);
  float e = __expf(2.f * t);
  float th = 1.f - 2.f / (e + 1.f);
  return 0.5f * v * (1.f + th);
}

__global__ __launch_bounds__(512, 2) void gemm1_kernel(
    const __hip_bfloat16* __restrict__ xb,
    const __hip_bfloat16* __restrict__ W1t,
    const float* __restrict__ b1,
    const int* __restrict__ IDX,
    __hip_bfloat16* __restrict__ h, int e0, int nblk) {
  __shared__ __align__(16) char smem[131072];
  int lin = blockIdx.x;
  { int q = nblk >> 3; lin = (lin & 7) * q + (lin >> 3); }  // XCD-contiguous
  const int tm = lin & 7, tn = (lin >> 3) & 15, ez = lin >> 7;
  const int e = e0 + ez;
  const int tid = threadIdx.x, wave = tid >> 6, lane = tid & 63;
  const int wm = wave >> 2, wn = wave & 3;
  const int lrow = lane & 15, lgrp = lane >> 4;

  const int r0 = tid >> 3;
  const int ksrc = (((tid & 7) - r0) & 7) * 16;  // inverse rotation on global src
  const char* pa[4]; const char* pb[4];
#pragma unroll
  for (int g = 0; g < 4; ++g) {
    int m = g * 64 + r0;
    int tok = IDX[e * CAP + tm * 256 + m];
    pa[g] = (const char*)(xb + (size_t)tok * DMODEL) + ksrc;
    int n = g * 64 + r0;
    pb[g] = (const char*)(W1t + ((size_t)e * DFF + tn * 256 + n) * DMODEL) + ksrc;
  }

  f32x4 acc[8][4];
  f32x4 zero = {0.f, 0.f, 0.f, 0.f};
#pragma unroll
  for (int mi = 0; mi < 8; ++mi)
#pragma unroll
    for (int ni = 0; ni < 4; ++ni) acc[mi][ni] = zero;

  gemm_core8<DMODEL / 64>(pa[0], pa[1], pa[2], pa[3],
                          pb[0], pb[1], pb[2], pb[3], smem, acc);

  // Epilogue: gelu -> bf16 -> XOR-swizzled LDS restage -> coalesced b128 stores
  __hip_bfloat16* he = h + (size_t)ez * CAP * DFF;
  const float* b1e = b1 + (size_t)e * DFF;
  float bvals[4];
#pragma unroll
  for (int ni = 0; ni < 4; ++ni)
    bvals[ni] = b1e[tn * 256 + wn * 64 + ni * 16 + lrow];
  char* sb = smem;
  const int wswz = lgrp << 5;  // ((row>>2)&3)<<5 == lgrp<<5 for our rows
#pragma unroll
  for (int mi = 0; mi < 8; ++mi) {
#pragma unroll
    for (int j = 0; j < 4; ++j) {
      int row = wm * 128 + mi * 16 + lgrp * 4 + j;
#pragma unroll
      for (int ni = 0; ni < 4; ++ni) {
        int col = wn * 64 + ni * 16 + lrow;
        float v = acc[mi][ni][j] + bvals[ni];
        v = gelu_tanh(v);
        *(__hip_bfloat16*)(sb + ((row * 512 + col * 2) ^ wswz)) =
            __float2bfloat16(v);
      }
    }
  }
  __syncthreads();
  size_t obase = (size_t)(tm * 256) * DFF + tn * 256;
#pragma unroll
  for (int c = 0; c < 16; ++c) {
    int byte = c * 8192 + tid * 16;
    int row = byte >> 9;
    int rswz = ((row >> 2) & 3) << 5;
    bf16x8 vals = *(const bf16x8*)(sb + (byte ^ rswz));
    int col = (byte & 511) >> 1;
    *(bf16x8*)(he + obase + (size_t)row * DFF + col) = vals;
  }
}

__global__ __launch_bounds__(512, 2) void gemm2_kernel(
    const __hip_bfloat16* __restrict__ h,
    const __hip_bfloat16* __restrict__ W2t,
    const float* __restrict__ b2,
    const int* __restrict__ IDX, const float* __restrict__ G,
    float* __restrict__ out, int e0, int nblk) {
  __shared__ __align__(16) char smem[131072];
  int lin = blockIdx.x;
  { int q = nblk >> 3; lin = (lin & 7) * q + (lin >> 3); }
  const int tm = lin & 7, tn = (lin >> 3) & 3, ez = lin >> 5;
  const int e = e0 + ez;
  const int tid = threadIdx.x, wave = tid >> 6, lane = tid & 63;
  const int wm = wave >> 2, wn = wave & 3;
  const int lrow = lane & 15, lgrp = lane >> 4;

  const int r0 = tid >> 3;
  const int ksrc = (((tid & 7) - r0) & 7) * 16;
  const char* pa[4]; const char* pb[4];
#pragma unroll
  for (int g = 0; g < 4; ++g) {
    int m = g * 64 + r0;
    pa[g] = (const char*)(h + ((size_t)ez * CAP + tm * 256 + m) * DFF) + ksrc;
    int n = g * 64 + r0;
    pb[g] = (const char*)(W2t + ((size_t)e * DMODEL + tn * 256 + n) * DFF) + ksrc;
  }

  f32x4 acc[8][4];
  f32x4 zero = {0.f, 0.f, 0.f, 0.f};
#pragma unroll
  for (int mi = 0; mi < 8; ++mi)
#pragma unroll
    for (int ni = 0; ni < 4; ++ni) acc[mi][ni] = zero;

  gemm_core8<DFF / 64>(pa[0], pa[1], pa[2], pa[3],
                       pb[0], pb[1], pb[2], pb[3], smem, acc);

  const float* b2e = b2 + (size_t)e * DMODEL;
  const int* idxe = IDX + (size_t)e * CAP;
  const float* ge = G + (size_t)e * CAP;
  float bvals[4];
#pragma unroll
  for (int ni = 0; ni < 4; ++ni)
    bvals[ni] = b2e[tn * 256 + wn * 64 + ni * 16 + lrow];
#pragma unroll
  for (int mi = 0; mi < 8; ++mi) {
#pragma unroll
    for (int j = 0; j < 4; ++j) {
      int row = tm * 256 + wm * 128 + mi * 16 + lgrp * 4 + j;
      float g = ge[row];
      int tok = idxe[row];
      float* orow = out + (size_t)tok * DMODEL;
#pragma unroll
      for (int ni = 0; ni < 4; ++ni) {
        int col = tn * 256 + wn * 64 + ni * 16 + lrow;
        atomicAdd(orow + col, (acc[mi][ni][j] + bvals[ni]) * g);
      }
    }
  }
}

extern "C" void kernel_launch(void* const* d_in, const int* in_sizes, int n_in,
                              void* d_out, int out_size, void* d_ws, size_t ws_size,
                              hipStream_t stream) {
  const float* x  = (const float*)d_in[0];
  const float* Wr = (const float*)d_in[1];
  const float* W1 = (const float*)d_in[2];
  const float* b1 = (const float*)d_in[3];
  const float* W2 = (const float*)d_in[4];
  const float* b2 = (const float*)d_in[5];
  float* out = (float*)d_out;
  char* ws = (char*)d_ws;

  size_t off = 0;
  float* scoresT = (float*)(ws + off); off += (size_t)NEXP * NTOK * 4;
  float* G       = (float*)(ws + off); off += (size_t)NEXP * CAP * 4;
  int*   IDX     = (int*)(ws + off);   off += (size_t)NEXP * CAP * 4;
  __hip_bfloat16* xb  = (__hip_bfloat16*)(ws + off); off += (size_t)NTOK * DMODEL * 2;
  __hip_bfloat16* W1t = (__hip_bfloat16*)(ws + off); off += (size_t)NEXP * DFF * DMODEL * 2;
  __hip_bfloat16* W2t = (__hip_bfloat16*)(ws + off); off += (size_t)NEXP * DMODEL * DFF * 2;
  __hip_bfloat16* hbuf = (__hip_bfloat16*)(ws + off);
  size_t h_per_e = (size_t)CAP * DFF * 2;
  size_t avail = (ws_size > off) ? (ws_size - off) : 0;
  int EC = (int)(avail / h_per_e);
  if (EC < 1) EC = 1;
  if (EC > NEXP) EC = NEXP;

  zero_f32<<<512, 256, 0, stream>>>(out, out_size / 4);
  router_kernel<<<NTOK / 4, 256, 0, stream>>>(x, Wr, scoresT, xb);
  topk_kernel<<<NEXP, 256, 0, stream>>>(scoresT, G, IDX);
  transpose_cvt<<<dim3(DFF / 32, DMODEL / 32, NEXP), dim3(32, 8), 0, stream>>>(
      W1, W1t, DMODEL, DFF);
  transpose_cvt<<<dim3(DMODEL / 32, DFF / 32, NEXP), dim3(32, 8), 0, stream>>>(
      W2, W2t, DFF, DMODEL);
  for (int e0 = 0; e0 < NEXP; e0 += EC) {
    int ne = (NEXP - e0 < EC) ? (NEXP - e0) : EC;
    int nblk1 = 128 * ne;
    gemm1_kernel<<<nblk1, 512, 0, stream>>>(xb, W1t, b1, IDX, hbuf, e0, nblk1);
    int nblk2 = 32 * ne;
    gemm2_kernel<<<nblk2, 512, 0, stream>>>(hbuf, W2t, b2, IDX, G, out, e0, nblk2);
  }
}

// Round 9
// 413.585 us; speedup vs baseline: 1.2578x; 1.1494x over previous
//
#include <hip/hip_runtime.h>
#include <hip/hip_bf16.h>
#include <cstdint>
#include <cstddef>

#define NTOK 8192
#define DMODEL 1024
#define DFF 4096
#define NEXP 8
#define CAP 2048

typedef __attribute__((ext_vector_type(8))) __bf16 bf16x8;
typedef __attribute__((ext_vector_type(4))) float f32x4;

__device__ __forceinline__ void gload16(const void* g, void* l) {
  __builtin_amdgcn_global_load_lds(
      (__attribute__((address_space(1))) void*)(g),
      (__attribute__((address_space(3))) void*)(l),
      16, 0, 0);
}
#define VMWAIT_(n) asm volatile("s_waitcnt vmcnt(" #n ")" ::: "memory")
#define VMWAIT(n) VMWAIT_(n)
#define MEMFENCE asm volatile("" ::: "memory")

__global__ __launch_bounds__(256) void zero_f32(float* p, int n4) {
  int i = blockIdx.x * blockDim.x + threadIdx.x;
  int stride = gridDim.x * blockDim.x;
  float4 z = make_float4(0.f, 0.f, 0.f, 0.f);
  for (; i < n4; i += stride) ((float4*)p)[i] = z;
}

__global__ __launch_bounds__(256) void router_kernel(
    const float* __restrict__ x, const float* __restrict__ Wr,
    float* __restrict__ scoresT, __hip_bfloat16* __restrict__ xb) {
  const int lane = threadIdx.x & 63;
  const int t = blockIdx.x * 4 + (threadIdx.x >> 6);
  const float* xr = x + (size_t)t * DMODEL;
  float acc[NEXP];
#pragma unroll
  for (int j = 0; j < NEXP; ++j) acc[j] = 0.f;
#pragma unroll
  for (int it = 0; it < DMODEL / 64; ++it) {
    int d = it * 64 + lane;
    float xv = xr[d];
    xb[(size_t)t * DMODEL + d] = __float2bfloat16(xv);
    const float4* w = (const float4*)(Wr + (size_t)d * NEXP);
    float4 w0 = w[0], w1 = w[1];
    acc[0] += xv * w0.x; acc[1] += xv * w0.y; acc[2] += xv * w0.z; acc[3] += xv * w0.w;
    acc[4] += xv * w1.x; acc[5] += xv * w1.y; acc[6] += xv * w1.z; acc[7] += xv * w1.w;
  }
#pragma unroll
  for (int off = 32; off; off >>= 1) {
#pragma unroll
    for (int j = 0; j < NEXP; ++j) acc[j] += __shfl_xor(acc[j], off);
  }
  float m = acc[0];
#pragma unroll
  for (int j = 1; j < NEXP; ++j) m = fmaxf(m, acc[j]);
  float s = 0.f;
#pragma unroll
  for (int j = 0; j < NEXP; ++j) { acc[j] = expf(acc[j] - m); s += acc[j]; }
  float inv = 1.f / s;
  if (lane < NEXP) scoresT[(size_t)lane * NTOK + t] = acc[lane] * inv;
}

// Exact top-k via 4-round radix-256 select; digit pick = parallel suffix scan.
__global__ __launch_bounds__(256) void topk_kernel(
    const float* __restrict__ scoresT, float* __restrict__ G, int* __restrict__ IDX) {
  __shared__ uint32_t sb[NTOK];
  __shared__ uint32_t hist[256];
  __shared__ uint32_t sfx[256];
  __shared__ uint32_t s_prefix, s_rem;
  __shared__ uint32_t eq_list[256];
  __shared__ uint32_t eq_cnt, gt_cnt;
  const int e = blockIdx.x, tid = threadIdx.x;
  const float* se = scoresT + (size_t)e * NTOK;
  for (int i = tid; i < NTOK; i += 256) sb[i] = __float_as_uint(se[i]);
  if (tid == 0) { s_prefix = 0u; s_rem = CAP; eq_cnt = 0u; gt_cnt = 0u; }
  __syncthreads();
  for (int r = 0; r < 4; ++r) {
    const int shift = 24 - 8 * r;
    hist[tid] = 0u;
    __syncthreads();
    uint32_t pfx = s_prefix;
    for (int i = tid; i < NTOK; i += 256) {
      uint32_t b = sb[i];
      if (((b >> shift) >> 8) == pfx) atomicAdd(&hist[(b >> shift) & 255u], 1u);
    }
    __syncthreads();
    sfx[tid] = hist[tid];
    __syncthreads();
#pragma unroll
    for (int off = 1; off < 256; off <<= 1) {
      uint32_t v = sfx[tid] + ((tid + off < 256) ? sfx[tid + off] : 0u);
      __syncthreads();
      sfx[tid] = v;
      __syncthreads();
    }
    uint32_t rem = s_rem;
    if (sfx[tid] >= rem && (tid == 255 || sfx[tid + 1] < rem)) {
      s_prefix = (pfx << 8) | (uint32_t)tid;
      s_rem = rem - ((tid == 255) ? 0u : sfx[tid + 1]);
    }
    __syncthreads();
  }
  const uint32_t T = s_prefix, need = s_rem;
  for (int i = tid; i < NTOK; i += 256) {
    uint32_t b = sb[i];
    if (b > T) {
      uint32_t p = atomicAdd(&gt_cnt, 1u);
      IDX[(size_t)e * CAP + p] = i;
      G[(size_t)e * CAP + p] = __uint_as_float(b);
    } else if (b == T) {
      uint32_t c = atomicAdd(&eq_cnt, 1u);
      if (c < 256u) eq_list[c] = (uint32_t)i;
    }
  }
  __syncthreads();
  if (tid == 0) {
    uint32_t base = gt_cnt;
    uint32_t c = eq_cnt < 256u ? eq_cnt : 256u;
    for (uint32_t s = 0; s < need; ++s) {
      uint32_t mv = 0xFFFFFFFFu; int mi = 0;
      for (uint32_t j = 0; j < c; ++j)
        if (eq_list[j] < mv) { mv = eq_list[j]; mi = (int)j; }
      eq_list[mi] = 0xFFFFFFFFu;
      IDX[(size_t)e * CAP + base + s] = (int)mv;
      G[(size_t)e * CAP + base + s] = __uint_as_float(T);
    }
  }
}

// Inverse CSR: for each (e,slot) entry, record it in the token's slot list.
__global__ __launch_bounds__(256) void build_inv(
    const int* __restrict__ IDX, int* __restrict__ cnt, int* __restrict__ inv) {
  int i = blockIdx.x * 256 + threadIdx.x;  // 0 .. E*CAP-1
  int t = IDX[i];
  int c = atomicAdd(&cnt[t], 1);
  inv[t * 8 + c] = i;
}

// Combine: out[t] = sum over contributions (already g-scaled bf16 rows of Xe).
__global__ __launch_bounds__(256) void combine_kernel(
    const __hip_bfloat16* __restrict__ Xe, const int* __restrict__ inv,
    const int* __restrict__ cnt, float* __restrict__ out) {
  const int w = (blockIdx.x * 256 + threadIdx.x) >> 6;  // token id
  const int lane = threadIdx.x & 63;
  const int c = cnt[w];
  float a[16];
#pragma unroll
  for (int i = 0; i < 16; ++i) a[i] = 0.f;
  for (int j = 0; j < c; ++j) {
    int s = inv[w * 8 + j];
    const bf16x8* p = (const bf16x8*)(Xe + (size_t)s * DMODEL + lane * 16);
    bf16x8 v0 = p[0], v1 = p[1];
#pragma unroll
    for (int i = 0; i < 8; ++i) {
      a[i] += (float)v0[i];
      a[8 + i] += (float)v1[i];
    }
  }
  float4* o = (float4*)(out + (size_t)w * DMODEL + lane * 16);
#pragma unroll
  for (int q = 0; q < 4; ++q)
    o[q] = make_float4(a[q * 4], a[q * 4 + 1], a[q * 4 + 2], a[q * 4 + 3]);
}

// Transpose + fp32->bf16: in [E][R][C] -> out [E][C][R].  64x64 tiles.
__global__ __launch_bounds__(256) void transpose_cvt(
    const float* __restrict__ in, __hip_bfloat16* __restrict__ out, int R, int C) {
  __shared__ float tile[64][68];
  const int e = blockIdx.z;
  const float* ine = in + (size_t)e * R * C;
  __hip_bfloat16* oute = out + (size_t)e * R * C;
  const int c0 = blockIdx.x * 64, r0 = blockIdx.y * 64;
  const int tid = threadIdx.x;
  const int lr = tid >> 4, lc = tid & 15;
#pragma unroll
  for (int it = 0; it < 4; ++it) {
    int row = it * 16 + lr;
    float4 v = *(const float4*)(ine + (size_t)(r0 + row) * C + c0 + lc * 4);
    *(float4*)&tile[row][lc * 4] = v;
  }
  __syncthreads();
  const int cc = tid >> 2, rq = tid & 3;
  unsigned short pk[16];
#pragma unroll
  for (int i = 0; i < 16; ++i) {
    __hip_bfloat16 b = __float2bfloat16(tile[rq * 16 + i][cc]);
    pk[i] = *(unsigned short*)&b;
  }
  char* dst = (char*)(oute + (size_t)(c0 + cc) * R + r0 + rq * 16);
  *(uint4*)dst = *(uint4*)&pk[0];
  *(uint4*)(dst + 16) = *(uint4*)&pk[8];
}

// ===== 256x256, BK=64, 8-phase / 2-K-tile pipeline (unchanged core) ==========
#define RD_A(BASE, H)                                                          \
  {                                                                            \
    _Pragma("unroll") for (int mi = 0; mi < 4; ++mi)                           \
        _Pragma("unroll") for (int ks = 0; ks < 2; ++ks) av[mi][ks] =          \
        *(const bf16x8*)((BASE) + Ab + offA[(H)*4 + mi][ks]);                  \
  }
#define RD_B(BASE, BV, H2)                                                     \
  {                                                                            \
    _Pragma("unroll") for (int ni = 0; ni < 2; ++ni)                           \
        _Pragma("unroll") for (int ks = 0; ks < 2; ++ks) BV[ni][ks] =          \
        *(const bf16x8*)((BASE) + Bb + offB[(H2)*2 + ni][ks]);                 \
  }
#define STAGE_A(H, BUF)                                                        \
  {                                                                            \
    gload16(pa[(H)*2], (BUF) + (H)*16384 + dst);                               \
    pa[(H)*2] += 128;                                                          \
    gload16(pa[(H)*2 + 1], (BUF) + (H)*16384 + 8192 + dst);                    \
    pa[(H)*2 + 1] += 128;                                                      \
  }
#define STAGE_B(H, BUF)                                                        \
  {                                                                            \
    gload16(pb[(H)*2], (BUF) + 32768 + (H)*16384 + dst);                       \
    pb[(H)*2] += 128;                                                          \
    gload16(pb[(H)*2 + 1], (BUF) + 32768 + (H)*16384 + 8192 + dst);            \
    pb[(H)*2 + 1] += 128;                                                      \
  }
#define PH_PRE                                                                 \
  __builtin_amdgcn_s_barrier();                                                \
  MEMFENCE;                                                                    \
  asm volatile("s_waitcnt lgkmcnt(0)" ::: "memory");                           \
  __builtin_amdgcn_sched_barrier(0);                                           \
  __builtin_amdgcn_s_setprio(1);
#define PH_POST __builtin_amdgcn_s_setprio(0);
#define MFMA_Q(MB, NB, BV)                                                     \
  {                                                                            \
    _Pragma("unroll") for (int mi = 0; mi < 4; ++mi)                           \
        _Pragma("unroll") for (int ni = 0; ni < 2; ++ni)                       \
            _Pragma("unroll") for (int ks = 0; ks < 2; ++ks)                   \
                acc[(MB) + mi][(NB) + ni] =                                    \
        __builtin_amdgcn_mfma_f32_16x16x32_bf16(                               \
            av[mi][ks], BV[ni][ks], acc[(MB) + mi][(NB) + ni], 0, 0, 0);       \
  }

template <int NKT>
__device__ __forceinline__ void gemm_core8(
    const char* pa0, const char* pa1, const char* pa2, const char* pa3,
    const char* pb0, const char* pb1, const char* pb2, const char* pb3,
    char* smem, f32x4 (&acc)[8][4]) {
  const int tid = threadIdx.x;
  const int wave = tid >> 6, lane = tid & 63;
  const int wm = wave >> 2, wn = wave & 3;
  const int lrow = lane & 15, lgrp = lane >> 4;
  const int dst = tid * 16;

  const char* pa[4] = {pa0, pa1, pa2, pa3};
  const char* pb[4] = {pb0, pb1, pb2, pb3};

  int offA[8][2], offB[4][2];
#pragma unroll
  for (int mi = 0; mi < 8; ++mi) {
    int rL = mi * 16 + lrow;
#pragma unroll
    for (int ks = 0; ks < 2; ++ks)
      offA[mi][ks] = rL * 128 + ((((ks * 4 + lgrp) + rL) & 7) << 4);
  }
#pragma unroll
  for (int ni = 0; ni < 4; ++ni) {
    int rL = (wn & 1) * 64 + ni * 16 + lrow;
#pragma unroll
    for (int ks = 0; ks < 2; ++ks)
      offB[ni][ks] = rL * 128 + ((((ks * 4 + lgrp) + rL) & 7) << 4);
  }
  const int Ab = wm * 16384;
  const int Bb = 32768 + (wn >> 1) * 16384;

  char* b0 = smem;
  char* b1 = smem + 65536;

#pragma unroll
  for (int g = 0; g < 4; ++g) {
    gload16(pa[g], b0 + (g >> 1) * 16384 + (g & 1) * 8192 + dst);
    pa[g] += 128;
  }
#pragma unroll
  for (int g = 0; g < 4; ++g) {
    gload16(pb[g], b0 + 32768 + (g >> 1) * 16384 + (g & 1) * 8192 + dst);
    pb[g] += 128;
  }
#pragma unroll
  for (int g = 0; g < 4; ++g) {
    gload16(pb[g], b1 + 32768 + (g >> 1) * 16384 + (g & 1) * 8192 + dst);
    pb[g] += 128;
  }
  VMWAIT(4);
  __builtin_amdgcn_s_barrier();
  MEMFENCE;

  bf16x8 av[4][2], bv0[2][2], bv1[2][2];

  for (int i = 0; i < NKT / 2; ++i) {
    const bool st2 = (2 * i + 2 < NKT);
    const bool st3 = (2 * i + 3 < NKT);

    RD_A(b0, 0); RD_B(b0, bv0, 0);
    STAGE_A(0, b1);
    PH_PRE; MFMA_Q(0, 0, bv0); PH_POST;

    RD_B(b0, bv1, 1);
    STAGE_A(1, b1);
    PH_PRE; MFMA_Q(0, 2, bv1); PH_POST;

    RD_A(b0, 1);
    if (st2) STAGE_B(0, b0);
    PH_PRE; MFMA_Q(4, 2, bv1); PH_POST;

    if (st2) STAGE_B(1, b0);
    PH_PRE; MFMA_Q(4, 0, bv0);
    __builtin_amdgcn_s_setprio(0);
    if (st2) { VMWAIT(4); } else { VMWAIT(0); }
    __builtin_amdgcn_s_barrier();
    MEMFENCE;

    RD_A(b1, 0); RD_B(b1, bv0, 0);
    if (st2) STAGE_A(0, b0);
    PH_PRE; MFMA_Q(0, 0, bv0); PH_POST;

    RD_B(b1, bv1, 1);
    if (st2) STAGE_A(1, b0);
    PH_PRE; MFMA_Q(0, 2, bv1); PH_POST;

    RD_A(b1, 1);
    if (st3) STAGE_B(0, b1);
    PH_PRE; MFMA_Q(4, 2, bv1); PH_POST;

    if (st3) STAGE_B(1, b1);
    PH_PRE; MFMA_Q(4, 0, bv0);
    __builtin_amdgcn_s_setprio(0);
    if (st3) { VMWAIT(4); }
    __builtin_amdgcn_s_barrier();
    MEMFENCE;
  }
}

__device__ __forceinline__ float gelu_tanh(float v) {
  float t = 0.7978845608028654f * (v + 0.044715f * v * v * v);
  float e = __expf(2.f * t);
  float th = 1.f - 2.f / (e + 1.f);
  return 0.5f * v * (1.f + th);
}

__global__ __launch_bounds__(512, 2) void gemm1_kernel(
    const __hip_bfloat16* __restrict__ xb,
    const __hip_bfloat16* __restrict__ W1t,
    const float* __restrict__ b1,
    const int* __restrict__ IDX,
    __hip_bfloat16* __restrict__ h, int e0, int nblk) {
  __shared__ __align__(16) char smem[131072];
  int lin = blockIdx.x;
  { int q = nblk >> 3; lin = (lin & 7) * q + (lin >> 3); }  // XCD-contiguous
  const int tm = lin & 7, tn = (lin >> 3) & 15, ez = lin >> 7;
  const int e = e0 + ez;
  const int tid = threadIdx.x, wave = tid >> 6, lane = tid & 63;
  const int wm = wave >> 2, wn = wave & 3;
  const int lrow = lane & 15, lgrp = lane >> 4;

  const int r0 = tid >> 3;
  const int ksrc = (((tid & 7) - r0) & 7) * 16;
  const char* pa[4]; const char* pb[4];
#pragma unroll
  for (int g = 0; g < 4; ++g) {
    int m = g * 64 + r0;
    int tok = IDX[e * CAP + tm * 256 + m];
    pa[g] = (const char*)(xb + (size_t)tok * DMODEL) + ksrc;
    int n = g * 64 + r0;
    pb[g] = (const char*)(W1t + ((size_t)e * DFF + tn * 256 + n) * DMODEL) + ksrc;
  }

  f32x4 acc[8][4];
  f32x4 zero = {0.f, 0.f, 0.f, 0.f};
#pragma unroll
  for (int mi = 0; mi < 8; ++mi)
#pragma unroll
    for (int ni = 0; ni < 4; ++ni) acc[mi][ni] = zero;

  gemm_core8<DMODEL / 64>(pa[0], pa[1], pa[2], pa[3],
                          pb[0], pb[1], pb[2], pb[3], smem, acc);

  __hip_bfloat16* he = h + (size_t)ez * CAP * DFF;
  const float* b1e = b1 + (size_t)e * DFF;
  float bvals[4];
#pragma unroll
  for (int ni = 0; ni < 4; ++ni)
    bvals[ni] = b1e[tn * 256 + wn * 64 + ni * 16 + lrow];
  char* sb = smem;
  const int wswz = lgrp << 5;
#pragma unroll
  for (int mi = 0; mi < 8; ++mi) {
#pragma unroll
    for (int j = 0; j < 4; ++j) {
      int row = wm * 128 + mi * 16 + lgrp * 4 + j;
#pragma unroll
      for (int ni = 0; ni < 4; ++ni) {
        int col = wn * 64 + ni * 16 + lrow;
        float v = acc[mi][ni][j] + bvals[ni];
        v = gelu_tanh(v);
        *(__hip_bfloat16*)(sb + ((row * 512 + col * 2) ^ wswz)) =
            __float2bfloat16(v);
      }
    }
  }
  __syncthreads();
  size_t obase = (size_t)(tm * 256) * DFF + tn * 256;
#pragma unroll
  for (int c = 0; c < 16; ++c) {
    int byte = c * 8192 + tid * 16;
    int row = byte >> 9;
    int rswz = ((row >> 2) & 3) << 5;
    bf16x8 vals = *(const bf16x8*)(sb + (byte ^ rswz));
    int col = (byte & 511) >> 1;
    *(bf16x8*)(he + obase + (size_t)row * DFF + col) = vals;
  }
}

__global__ __launch_bounds__(512, 2) void gemm2_kernel(
    const __hip_bfloat16* __restrict__ h,
    const __hip_bfloat16* __restrict__ W2t,
    const float* __restrict__ b2,
    const float* __restrict__ G,
    __hip_bfloat16* __restrict__ Xe, int e0, int nblk) {
  __shared__ __align__(16) char smem[131072];
  int lin = blockIdx.x;
  { int q = nblk >> 3; lin = (lin & 7) * q + (lin >> 3); }
  const int tm = lin & 7, tn = (lin >> 3) & 3, ez = lin >> 5;
  const int e = e0 + ez;
  const int tid = threadIdx.x, wave = tid >> 6, lane = tid & 63;
  const int wm = wave >> 2, wn = wave & 3;
  const int lrow = lane & 15, lgrp = lane >> 4;

  const int r0 = tid >> 3;
  const int ksrc = (((tid & 7) - r0) & 7) * 16;
  const char* pa[4]; const char* pb[4];
#pragma unroll
  for (int g = 0; g < 4; ++g) {
    int m = g * 64 + r0;
    pa[g] = (const char*)(h + ((size_t)ez * CAP + tm * 256 + m) * DFF) + ksrc;
    int n = g * 64 + r0;
    pb[g] = (const char*)(W2t + ((size_t)e * DMODEL + tn * 256 + n) * DFF) + ksrc;
  }

  f32x4 acc[8][4];
  f32x4 zero = {0.f, 0.f, 0.f, 0.f};
#pragma unroll
  for (int mi = 0; mi < 8; ++mi)
#pragma unroll
    for (int ni = 0; ni < 4; ++ni) acc[mi][ni] = zero;

  gemm_core8<DFF / 64>(pa[0], pa[1], pa[2], pa[3],
                       pb[0], pb[1], pb[2], pb[3], smem, acc);

  // Epilogue: (acc + b2) * g -> bf16 -> swizzled LDS restage -> coalesced store
  const float* b2e = b2 + (size_t)e * DMODEL;
  const float* ge = G + (size_t)e * CAP + tm * 256;
  float bvals[4];
#pragma unroll
  for (int ni = 0; ni < 4; ++ni)
    bvals[ni] = b2e[tn * 256 + wn * 64 + ni * 16 + lrow];
  char* sb = smem;
  const int wswz = lgrp << 5;
#pragma unroll
  for (int mi = 0; mi < 8; ++mi) {
#pragma unroll
    for (int j = 0; j < 4; ++j) {
      int row = wm * 128 + mi * 16 + lgrp * 4 + j;
      float g = ge[row];
#pragma unroll
      for (int ni = 0; ni < 4; ++ni) {
        int col = wn * 64 + ni * 16 + lrow;
        float v = (acc[mi][ni][j] + bvals[ni]) * g;
        *(__hip_bfloat16*)(sb + ((row * 512 + col * 2) ^ wswz)) =
            __float2bfloat16(v);
      }
    }
  }
  __syncthreads();
  __hip_bfloat16* xbase = Xe + ((size_t)(e * CAP + tm * 256)) * DMODEL + tn * 256;
#pragma unroll
  for (int c = 0; c < 16; ++c) {
    int byte = c * 8192 + tid * 16;
    int row = byte >> 9;
    int rswz = ((row >> 2) & 3) << 5;
    bf16x8 vals = *(const bf16x8*)(sb + (byte ^ rswz));
    int col = (byte & 511) >> 1;
    *(bf16x8*)(xbase + (size_t)row * DMODEL + col) = vals;
  }
}

extern "C" void kernel_launch(void* const* d_in, const int* in_sizes, int n_in,
                              void* d_out, int out_size, void* d_ws, size_t ws_size,
                              hipStream_t stream) {
  const float* x  = (const float*)d_in[0];
  const float* Wr = (const float*)d_in[1];
  const float* W1 = (const float*)d_in[2];
  const float* b1 = (const float*)d_in[3];
  const float* W2 = (const float*)d_in[4];
  const float* b2 = (const float*)d_in[5];
  float* out = (float*)d_out;
  char* ws = (char*)d_ws;

  size_t off = 0;
  float* scoresT = (float*)(ws + off); off += (size_t)NEXP * NTOK * 4;
  float* G       = (float*)(ws + off); off += (size_t)NEXP * CAP * 4;
  int*   IDX     = (int*)(ws + off);   off += (size_t)NEXP * CAP * 4;
  int*   cnt     = (int*)(ws + off);   off += (size_t)NTOK * 4;
  int*   inv     = (int*)(ws + off);   off += (size_t)NTOK * 8 * 4;
  __hip_bfloat16* xb  = (__hip_bfloat16*)(ws + off); off += (size_t)NTOK * DMODEL * 2;
  __hip_bfloat16* W1t = (__hip_bfloat16*)(ws + off); off += (size_t)NEXP * DFF * DMODEL * 2;
  __hip_bfloat16* W2t = (__hip_bfloat16*)(ws + off); off += (size_t)NEXP * DMODEL * DFF * 2;
  __hip_bfloat16* Xe  = (__hip_bfloat16*)(ws + off); off += (size_t)NEXP * CAP * DMODEL * 2;
  __hip_bfloat16* hbuf = (__hip_bfloat16*)(ws + off);
  size_t h_per_e = (size_t)CAP * DFF * 2;
  size_t avail = (ws_size > off) ? (ws_size - off) : 0;
  int EC = (int)(avail / h_per_e);
  if (EC < 1) EC = 1;
  if (EC > NEXP) EC = NEXP;

  zero_f32<<<8, 256, 0, stream>>>((float*)cnt, NTOK / 4);
  router_kernel<<<NTOK / 4, 256, 0, stream>>>(x, Wr, scoresT, xb);
  topk_kernel<<<NEXP, 256, 0, stream>>>(scoresT, G, IDX);
  build_inv<<<NEXP * CAP / 256, 256, 0, stream>>>(IDX, cnt, inv);
  transpose_cvt<<<dim3(DFF / 64, DMODEL / 64, NEXP), 256, 0, stream>>>(
      W1, W1t, DMODEL, DFF);
  transpose_cvt<<<dim3(DMODEL / 64, DFF / 64, NEXP), 256, 0, stream>>>(
      W2, W2t, DFF, DMODEL);
  for (int e0 = 0; e0 < NEXP; e0 += EC) {
    int ne = (NEXP - e0 < EC) ? (NEXP - e0) : EC;
    int nblk1 = 128 * ne;
    gemm1_kernel<<<nblk1, 512, 0, stream>>>(xb, W1t, b1, IDX, hbuf, e0, nblk1);
    int nblk2 = 32 * ne;
    gemm2_kernel<<<nblk2, 512, 0, stream>>>(hbuf, W2t, b2, G, Xe, e0, nblk2);
  }
  combine_kernel<<<NTOK / 4, 256, 0, stream>>>(Xe, inv, cnt, out);
}

// Round 10
// 412.877 us; speedup vs baseline: 1.2600x; 1.0017x over previous
//
#include <hip/hip_runtime.h>
#include <hip/hip_bf16.h>
#include <cstdint>
#include <cstddef>

#define NTOK 8192
#define DMODEL 1024
#define DFF 4096
#define NEXP 8
#define CAP 2048

typedef __attribute__((ext_vector_type(8))) __bf16 bf16x8;
typedef __attribute__((ext_vector_type(4))) float f32x4;

__device__ __forceinline__ void gload16(const void* g, void* l) {
  __builtin_amdgcn_global_load_lds(
      (__attribute__((address_space(1))) void*)(g),
      (__attribute__((address_space(3))) void*)(l),
      16, 0, 0);
}
#define VMWAIT_(n) asm volatile("s_waitcnt vmcnt(" #n ")" ::: "memory")
#define VMWAIT(n) VMWAIT_(n)
#define MEMFENCE asm volatile("" ::: "memory")

__global__ __launch_bounds__(256) void zero_f32(float* p, int n4) {
  int i = blockIdx.x * blockDim.x + threadIdx.x;
  int stride = gridDim.x * blockDim.x;
  float4 z = make_float4(0.f, 0.f, 0.f, 0.f);
  for (; i < n4; i += stride) ((float4*)p)[i] = z;
}

__global__ __launch_bounds__(256) void router_kernel(
    const float* __restrict__ x, const float* __restrict__ Wr,
    float* __restrict__ scoresT, __hip_bfloat16* __restrict__ xb) {
  const int lane = threadIdx.x & 63;
  const int t = blockIdx.x * 4 + (threadIdx.x >> 6);
  const float* xr = x + (size_t)t * DMODEL;
  float acc[NEXP];
#pragma unroll
  for (int j = 0; j < NEXP; ++j) acc[j] = 0.f;
#pragma unroll
  for (int it = 0; it < DMODEL / 64; ++it) {
    int d = it * 64 + lane;
    float xv = xr[d];
    xb[(size_t)t * DMODEL + d] = __float2bfloat16(xv);
    const float4* w = (const float4*)(Wr + (size_t)d * NEXP);
    float4 w0 = w[0], w1 = w[1];
    acc[0] += xv * w0.x; acc[1] += xv * w0.y; acc[2] += xv * w0.z; acc[3] += xv * w0.w;
    acc[4] += xv * w1.x; acc[5] += xv * w1.y; acc[6] += xv * w1.z; acc[7] += xv * w1.w;
  }
#pragma unroll
  for (int off = 32; off; off >>= 1) {
#pragma unroll
    for (int j = 0; j < NEXP; ++j) acc[j] += __shfl_xor(acc[j], off);
  }
  float m = acc[0];
#pragma unroll
  for (int j = 1; j < NEXP; ++j) m = fmaxf(m, acc[j]);
  float s = 0.f;
#pragma unroll
  for (int j = 0; j < NEXP; ++j) { acc[j] = expf(acc[j] - m); s += acc[j]; }
  float inv = 1.f / s;
  if (lane < NEXP) scoresT[(size_t)lane * NTOK + t] = acc[lane] * inv;
}

// Exact top-k via 4-round radix-256 select; digit pick = parallel suffix scan.
__global__ __launch_bounds__(256) void topk_kernel(
    const float* __restrict__ scoresT, float* __restrict__ G, int* __restrict__ IDX) {
  __shared__ uint32_t sb[NTOK];
  __shared__ uint32_t hist[256];
  __shared__ uint32_t sfx[256];
  __shared__ uint32_t s_prefix, s_rem;
  __shared__ uint32_t eq_list[256];
  __shared__ uint32_t eq_cnt, gt_cnt;
  const int e = blockIdx.x, tid = threadIdx.x;
  const float* se = scoresT + (size_t)e * NTOK;
  for (int i = tid; i < NTOK; i += 256) sb[i] = __float_as_uint(se[i]);
  if (tid == 0) { s_prefix = 0u; s_rem = CAP; eq_cnt = 0u; gt_cnt = 0u; }
  __syncthreads();
  for (int r = 0; r < 4; ++r) {
    const int shift = 24 - 8 * r;
    hist[tid] = 0u;
    __syncthreads();
    uint32_t pfx = s_prefix;
    for (int i = tid; i < NTOK; i += 256) {
      uint32_t b = sb[i];
      if (((b >> shift) >> 8) == pfx) atomicAdd(&hist[(b >> shift) & 255u], 1u);
    }
    __syncthreads();
    sfx[tid] = hist[tid];
    __syncthreads();
#pragma unroll
    for (int off = 1; off < 256; off <<= 1) {
      uint32_t v = sfx[tid] + ((tid + off < 256) ? sfx[tid + off] : 0u);
      __syncthreads();
      sfx[tid] = v;
      __syncthreads();
    }
    uint32_t rem = s_rem;
    if (sfx[tid] >= rem && (tid == 255 || sfx[tid + 1] < rem)) {
      s_prefix = (pfx << 8) | (uint32_t)tid;
      s_rem = rem - ((tid == 255) ? 0u : sfx[tid + 1]);
    }
    __syncthreads();
  }
  const uint32_t T = s_prefix, need = s_rem;
  for (int i = tid; i < NTOK; i += 256) {
    uint32_t b = sb[i];
    if (b > T) {
      uint32_t p = atomicAdd(&gt_cnt, 1u);
      IDX[(size_t)e * CAP + p] = i;
      G[(size_t)e * CAP + p] = __uint_as_float(b);
    } else if (b == T) {
      uint32_t c = atomicAdd(&eq_cnt, 1u);
      if (c < 256u) eq_list[c] = (uint32_t)i;
    }
  }
  __syncthreads();
  if (tid == 0) {
    uint32_t base = gt_cnt;
    uint32_t c = eq_cnt < 256u ? eq_cnt : 256u;
    for (uint32_t s = 0; s < need; ++s) {
      uint32_t mv = 0xFFFFFFFFu; int mi = 0;
      for (uint32_t j = 0; j < c; ++j)
        if (eq_list[j] < mv) { mv = eq_list[j]; mi = (int)j; }
      eq_list[mi] = 0xFFFFFFFFu;
      IDX[(size_t)e * CAP + base + s] = (int)mv;
      G[(size_t)e * CAP + base + s] = __uint_as_float(T);
    }
  }
}

// Inverse CSR: for each (e,slot) entry, record it in the token's slot list.
__global__ __launch_bounds__(256) void build_inv(
    const int* __restrict__ IDX, int* __restrict__ cnt, int* __restrict__ inv) {
  int i = blockIdx.x * 256 + threadIdx.x;  // 0 .. E*CAP-1
  int t = IDX[i];
  int c = atomicAdd(&cnt[t], 1);
  inv[t * 8 + c] = i;
}

// Combine: out[t] = sum over contributions (already g-scaled bf16 rows of Xe).
__global__ __launch_bounds__(256) void combine_kernel(
    const __hip_bfloat16* __restrict__ Xe, const int* __restrict__ inv,
    const int* __restrict__ cnt, float* __restrict__ out) {
  const int w = (blockIdx.x * 256 + threadIdx.x) >> 6;  // token id
  const int lane = threadIdx.x & 63;
  const int c = cnt[w];
  float a[16];
#pragma unroll
  for (int i = 0; i < 16; ++i) a[i] = 0.f;
  for (int j = 0; j < c; ++j) {
    int s = inv[w * 8 + j];
    const bf16x8* p = (const bf16x8*)(Xe + (size_t)s * DMODEL + lane * 16);
    bf16x8 v0 = p[0], v1 = p[1];
#pragma unroll
    for (int i = 0; i < 8; ++i) {
      a[i] += (float)v0[i];
      a[8 + i] += (float)v1[i];
    }
  }
  float4* o = (float4*)(out + (size_t)w * DMODEL + lane * 16);
#pragma unroll
  for (int q = 0; q < 4; ++q)
    o[q] = make_float4(a[q * 4], a[q * 4 + 1], a[q * 4 + 2], a[q * 4 + 3]);
}

// Transpose + fp32->bf16: in [E][R][C] -> out [E][C][R].  64x64 tiles.
__global__ __launch_bounds__(256) void transpose_cvt(
    const float* __restrict__ in, __hip_bfloat16* __restrict__ out, int R, int C) {
  __shared__ float tile[64][68];
  const int e = blockIdx.z;
  const float* ine = in + (size_t)e * R * C;
  __hip_bfloat16* oute = out + (size_t)e * R * C;
  const int c0 = blockIdx.x * 64, r0 = blockIdx.y * 64;
  const int tid = threadIdx.x;
  const int lr = tid >> 4, lc = tid & 15;
#pragma unroll
  for (int it = 0; it < 4; ++it) {
    int row = it * 16 + lr;
    float4 v = *(const float4*)(ine + (size_t)(r0 + row) * C + c0 + lc * 4);
    *(float4*)&tile[row][lc * 4] = v;
  }
  __syncthreads();
  const int cc = tid >> 2, rq = tid & 3;
  unsigned short pk[16];
#pragma unroll
  for (int i = 0; i < 16; ++i) {
    __hip_bfloat16 b = __float2bfloat16(tile[rq * 16 + i][cc]);
    pk[i] = *(unsigned short*)&b;
  }
  char* dst = (char*)(oute + (size_t)(c0 + cc) * R + r0 + rq * 16);
  *(uint4*)dst = *(uint4*)&pk[0];
  *(uint4*)(dst + 16) = *(uint4*)&pk[8];
}

// ===== 256x256, BK=64, 8-phase / 2-K-tile pipeline =====
// A/B: no explicit lgkm drain / sched_barrier before MFMA clusters — compiler
// emits fine-grained lgkmcnt between ds_reads and MFMAs (m97/m141 lesson).
// Cross-wave staging hazards still carried by ph4/ph8 VMWAIT(4)+barrier gates.
#define RD_A(BASE, H)                                                          \
  {                                                                            \
    _Pragma("unroll") for (int mi = 0; mi < 4; ++mi)                           \
        _Pragma("unroll") for (int ks = 0; ks < 2; ++ks) av[mi][ks] =          \
        *(const bf16x8*)((BASE) + Ab + offA[(H)*4 + mi][ks]);                  \
  }
#define RD_B(BASE, BV, H2)                                                     \
  {                                                                            \
    _Pragma("unroll") for (int ni = 0; ni < 2; ++ni)                           \
        _Pragma("unroll") for (int ks = 0; ks < 2; ++ks) BV[ni][ks] =          \
        *(const bf16x8*)((BASE) + Bb + offB[(H2)*2 + ni][ks]);                 \
  }
#define STAGE_A(H, BUF)                                                        \
  {                                                                            \
    gload16(pa[(H)*2], (BUF) + (H)*16384 + dst);                               \
    pa[(H)*2] += 128;                                                          \
    gload16(pa[(H)*2 + 1], (BUF) + (H)*16384 + 8192 + dst);                    \
    pa[(H)*2 + 1] += 128;                                                      \
  }
#define STAGE_B(H, BUF)                                                        \
  {                                                                            \
    gload16(pb[(H)*2], (BUF) + 32768 + (H)*16384 + dst);                       \
    pb[(H)*2] += 128;                                                          \
    gload16(pb[(H)*2 + 1], (BUF) + 32768 + (H)*16384 + 8192 + dst);            \
    pb[(H)*2 + 1] += 128;                                                      \
  }
#define PH_PRE                                                                 \
  __builtin_amdgcn_s_barrier();                                                \
  MEMFENCE;                                                                    \
  __builtin_amdgcn_s_setprio(1);
#define PH_POST __builtin_amdgcn_s_setprio(0);
#define MFMA_Q(MB, NB, BV)                                                     \
  {                                                                            \
    _Pragma("unroll") for (int mi = 0; mi < 4; ++mi)                           \
        _Pragma("unroll") for (int ni = 0; ni < 2; ++ni)                       \
            _Pragma("unroll") for (int ks = 0; ks < 2; ++ks)                   \
                acc[(MB) + mi][(NB) + ni] =                                    \
        __builtin_amdgcn_mfma_f32_16x16x32_bf16(                               \
            av[mi][ks], BV[ni][ks], acc[(MB) + mi][(NB) + ni], 0, 0, 0);       \
  }

template <int NKT>
__device__ __forceinline__ void gemm_core8(
    const char* pa0, const char* pa1, const char* pa2, const char* pa3,
    const char* pb0, const char* pb1, const char* pb2, const char* pb3,
    char* smem, f32x4 (&acc)[8][4]) {
  const int tid = threadIdx.x;
  const int wave = tid >> 6, lane = tid & 63;
  const int wm = wave >> 2, wn = wave & 3;
  const int lrow = lane & 15, lgrp = lane >> 4;
  const int dst = tid * 16;

  const char* pa[4] = {pa0, pa1, pa2, pa3};
  const char* pb[4] = {pb0, pb1, pb2, pb3};

  int offA[8][2], offB[4][2];
#pragma unroll
  for (int mi = 0; mi < 8; ++mi) {
    int rL = mi * 16 + lrow;
#pragma unroll
    for (int ks = 0; ks < 2; ++ks)
      offA[mi][ks] = rL * 128 + ((((ks * 4 + lgrp) + rL) & 7) << 4);
  }
#pragma unroll
  for (int ni = 0; ni < 4; ++ni) {
    int rL = (wn & 1) * 64 + ni * 16 + lrow;
#pragma unroll
    for (int ks = 0; ks < 2; ++ks)
      offB[ni][ks] = rL * 128 + ((((ks * 4 + lgrp) + rL) & 7) << 4);
  }
  const int Ab = wm * 16384;
  const int Bb = 32768 + (wn >> 1) * 16384;

  char* b0 = smem;
  char* b1 = smem + 65536;

#pragma unroll
  for (int g = 0; g < 4; ++g) {
    gload16(pa[g], b0 + (g >> 1) * 16384 + (g & 1) * 8192 + dst);
    pa[g] += 128;
  }
#pragma unroll
  for (int g = 0; g < 4; ++g) {
    gload16(pb[g], b0 + 32768 + (g >> 1) * 16384 + (g & 1) * 8192 + dst);
    pb[g] += 128;
  }
#pragma unroll
  for (int g = 0; g < 4; ++g) {
    gload16(pb[g], b1 + 32768 + (g >> 1) * 16384 + (g & 1) * 8192 + dst);
    pb[g] += 128;
  }
  VMWAIT(4);
  __builtin_amdgcn_s_barrier();
  MEMFENCE;

  bf16x8 av[4][2], bv0[2][2], bv1[2][2];

  for (int i = 0; i < NKT / 2; ++i) {
    const bool st2 = (2 * i + 2 < NKT);
    const bool st3 = (2 * i + 3 < NKT);

    RD_A(b0, 0); RD_B(b0, bv0, 0);
    STAGE_A(0, b1);
    PH_PRE; MFMA_Q(0, 0, bv0); PH_POST;

    RD_B(b0, bv1, 1);
    STAGE_A(1, b1);
    PH_PRE; MFMA_Q(0, 2, bv1); PH_POST;

    RD_A(b0, 1);
    if (st2) STAGE_B(0, b0);
    PH_PRE; MFMA_Q(4, 2, bv1); PH_POST;

    if (st2) STAGE_B(1, b0);
    PH_PRE; MFMA_Q(4, 0, bv0);
    __builtin_amdgcn_s_setprio(0);
    if (st2) { VMWAIT(4); } else { VMWAIT(0); }
    __builtin_amdgcn_s_barrier();
    MEMFENCE;

    RD_A(b1, 0); RD_B(b1, bv0, 0);
    if (st2) STAGE_A(0, b0);
    PH_PRE; MFMA_Q(0, 0, bv0); PH_POST;

    RD_B(b1, bv1, 1);
    if (st2) STAGE_A(1, b0);
    PH_PRE; MFMA_Q(0, 2, bv1); PH_POST;

    RD_A(b1, 1);
    if (st3) STAGE_B(0, b1);
    PH_PRE; MFMA_Q(4, 2, bv1); PH_POST;

    if (st3) STAGE_B(1, b1);
    PH_PRE; MFMA_Q(4, 0, bv0);
    __builtin_amdgcn_s_setprio(0);
    if (st3) { VMWAIT(4); }
    __builtin_amdgcn_s_barrier();
    MEMFENCE;
  }
}

__device__ __forceinline__ float gelu_tanh(float v) {
  float t = 0.7978845608028654f * (v + 0.044715f * v * v * v);
  float e = __expf(2.f * t);
  float th = 1.f - 2.f / (e + 1.f);
  return 0.5f * v * (1.f + th);
}

__global__ __launch_bounds__(512, 2) void gemm1_kernel(
    const __hip_bfloat16* __restrict__ xb,
    const __hip_bfloat16* __restrict__ W1t,
    const float* __restrict__ b1,
    const int* __restrict__ IDX,
    __hip_bfloat16* __restrict__ h, int e0, int nblk) {
  __shared__ __align__(16) char smem[131072];
  int lin = blockIdx.x;
  { int q = nblk >> 3; lin = (lin & 7) * q + (lin >> 3); }  // XCD-contiguous
  const int tm = lin & 7, tn = (lin >> 3) & 15, ez = lin >> 7;
  const int e = e0 + ez;
  const int tid = threadIdx.x, wave = tid >> 6, lane = tid & 63;
  const int wm = wave >> 2, wn = wave & 3;
  const int lrow = lane & 15, lgrp = lane >> 4;

  const int r0 = tid >> 3;
  const int ksrc = (((tid & 7) - r0) & 7) * 16;
  const char* pa[4]; const char* pb[4];
#pragma unroll
  for (int g = 0; g < 4; ++g) {
    int m = g * 64 + r0;
    int tok = IDX[e * CAP + tm * 256 + m];
    pa[g] = (const char*)(xb + (size_t)tok * DMODEL) + ksrc;
    int n = g * 64 + r0;
    pb[g] = (const char*)(W1t + ((size_t)e * DFF + tn * 256 + n) * DMODEL) + ksrc;
  }

  f32x4 acc[8][4];
  f32x4 zero = {0.f, 0.f, 0.f, 0.f};
#pragma unroll
  for (int mi = 0; mi < 8; ++mi)
#pragma unroll
    for (int ni = 0; ni < 4; ++ni) acc[mi][ni] = zero;

  gemm_core8<DMODEL / 64>(pa[0], pa[1], pa[2], pa[3],
                          pb[0], pb[1], pb[2], pb[3], smem, acc);

  __hip_bfloat16* he = h + (size_t)ez * CAP * DFF;
  const float* b1e = b1 + (size_t)e * DFF;
  float bvals[4];
#pragma unroll
  for (int ni = 0; ni < 4; ++ni)
    bvals[ni] = b1e[tn * 256 + wn * 64 + ni * 16 + lrow];
  char* sb = smem;
  const int wswz = lgrp << 5;
#pragma unroll
  for (int mi = 0; mi < 8; ++mi) {
#pragma unroll
    for (int j = 0; j < 4; ++j) {
      int row = wm * 128 + mi * 16 + lgrp * 4 + j;
#pragma unroll
      for (int ni = 0; ni < 4; ++ni) {
        int col = wn * 64 + ni * 16 + lrow;
        float v = acc[mi][ni][j] + bvals[ni];
        v = gelu_tanh(v);
        *(__hip_bfloat16*)(sb + ((row * 512 + col * 2) ^ wswz)) =
            __float2bfloat16(v);
      }
    }
  }
  __syncthreads();
  size_t obase = (size_t)(tm * 256) * DFF + tn * 256;
#pragma unroll
  for (int c = 0; c < 16; ++c) {
    int byte = c * 8192 + tid * 16;
    int row = byte >> 9;
    int rswz = ((row >> 2) & 3) << 5;
    bf16x8 vals = *(const bf16x8*)(sb + (byte ^ rswz));
    int col = (byte & 511) >> 1;
    *(bf16x8*)(he + obase + (size_t)row * DFF + col) = vals;
  }
}

__global__ __launch_bounds__(512, 2) void gemm2_kernel(
    const __hip_bfloat16* __restrict__ h,
    const __hip_bfloat16* __restrict__ W2t,
    const float* __restrict__ b2,
    const float* __restrict__ G,
    __hip_bfloat16* __restrict__ Xe, int e0, int nblk) {
  __shared__ __align__(16) char smem[131072];
  int lin = blockIdx.x;
  { int q = nblk >> 3; lin = (lin & 7) * q + (lin >> 3); }
  const int tm = lin & 7, tn = (lin >> 3) & 3, ez = lin >> 5;
  const int e = e0 + ez;
  const int tid = threadIdx.x, wave = tid >> 6, lane = tid & 63;
  const int wm = wave >> 2, wn = wave & 3;
  const int lrow = lane & 15, lgrp = lane >> 4;

  const int r0 = tid >> 3;
  const int ksrc = (((tid & 7) - r0) & 7) * 16;
  const char* pa[4]; const char* pb[4];
#pragma unroll
  for (int g = 0; g < 4; ++g) {
    int m = g * 64 + r0;
    pa[g] = (const char*)(h + ((size_t)ez * CAP + tm * 256 + m) * DFF) + ksrc;
    int n = g * 64 + r0;
    pb[g] = (const char*)(W2t + ((size_t)e * DMODEL + tn * 256 + n) * DFF) + ksrc;
  }

  f32x4 acc[8][4];
  f32x4 zero = {0.f, 0.f, 0.f, 0.f};
#pragma unroll
  for (int mi = 0; mi < 8; ++mi)
#pragma unroll
    for (int ni = 0; ni < 4; ++ni) acc[mi][ni] = zero;

  gemm_core8<DFF / 64>(pa[0], pa[1], pa[2], pa[3],
                       pb[0], pb[1], pb[2], pb[3], smem, acc);

  const float* b2e = b2 + (size_t)e * DMODEL;
  const float* ge = G + (size_t)e * CAP + tm * 256;
  float bvals[4];
#pragma unroll
  for (int ni = 0; ni < 4; ++ni)
    bvals[ni] = b2e[tn * 256 + wn * 64 + ni * 16 + lrow];
  char* sb = smem;
  const int wswz = lgrp << 5;
#pragma unroll
  for (int mi = 0; mi < 8; ++mi) {
#pragma unroll
    for (int j = 0; j < 4; ++j) {
      int row = wm * 128 + mi * 16 + lgrp * 4 + j;
      float g = ge[row];
#pragma unroll
      for (int ni = 0; ni < 4; ++ni) {
        int col = wn * 64 + ni * 16 + lrow;
        float v = (acc[mi][ni][j] + bvals[ni]) * g;
        *(__hip_bfloat16*)(sb + ((row * 512 + col * 2) ^ wswz)) =
            __float2bfloat16(v);
      }
    }
  }
  __syncthreads();
  __hip_bfloat16* xbase = Xe + ((size_t)(e * CAP + tm * 256)) * DMODEL + tn * 256;
#pragma unroll
  for (int c = 0; c < 16; ++c) {
    int byte = c * 8192 + tid * 16;
    int row = byte >> 9;
    int rswz = ((row >> 2) & 3) << 5;
    bf16x8 vals = *(const bf16x8*)(sb + (byte ^ rswz));
    int col = (byte & 511) >> 1;
    *(bf16x8*)(xbase + (size_t)row * DMODEL + col) = vals;
  }
}

extern "C" void kernel_launch(void* const* d_in, const int* in_sizes, int n_in,
                              void* d_out, int out_size, void* d_ws, size_t ws_size,
                              hipStream_t stream) {
  const float* x  = (const float*)d_in[0];
  const float* Wr = (const float*)d_in[1];
  const float* W1 = (const float*)d_in[2];
  const float* b1 = (const float*)d_in[3];
  const float* W2 = (const float*)d_in[4];
  const float* b2 = (const float*)d_in[5];
  float* out = (float*)d_out;
  char* ws = (char*)d_ws;

  size_t off = 0;
  float* scoresT = (float*)(ws + off); off += (size_t)NEXP * NTOK * 4;
  float* G       = (float*)(ws + off); off += (size_t)NEXP * CAP * 4;
  int*   IDX     = (int*)(ws + off);   off += (size_t)NEXP * CAP * 4;
  int*   cnt     = (int*)(ws + off);   off += (size_t)NTOK * 4;
  int*   inv     = (int*)(ws + off);   off += (size_t)NTOK * 8 * 4;
  __hip_bfloat16* xb  = (__hip_bfloat16*)(ws + off); off += (size_t)NTOK * DMODEL * 2;
  __hip_bfloat16* W1t = (__hip_bfloat16*)(ws + off); off += (size_t)NEXP * DFF * DMODEL * 2;
  __hip_bfloat16* W2t = (__hip_bfloat16*)(ws + off); off += (size_t)NEXP * DMODEL * DFF * 2;
  __hip_bfloat16* Xe  = (__hip_bfloat16*)(ws + off); off += (size_t)NEXP * CAP * DMODEL * 2;
  __hip_bfloat16* hbuf = (__hip_bfloat16*)(ws + off);
  size_t h_per_e = (size_t)CAP * DFF * 2;
  size_t avail = (ws_size > off) ? (ws_size - off) : 0;
  int EC = (int)(avail / h_per_e);
  if (EC < 1) EC = 1;
  if (EC > NEXP) EC = NEXP;

  zero_f32<<<8, 256, 0, stream>>>((float*)cnt, NTOK / 4);
  router_kernel<<<NTOK / 4, 256, 0, stream>>>(x, Wr, scoresT, xb);
  topk_kernel<<<NEXP, 256, 0, stream>>>(scoresT, G, IDX);
  build_inv<<<NEXP * CAP / 256, 256, 0, stream>>>(IDX, cnt, inv);
  transpose_cvt<<<dim3(DFF / 64, DMODEL / 64, NEXP), 256, 0, stream>>>(
      W1, W1t, DMODEL, DFF);
  transpose_cvt<<<dim3(DMODEL / 64, DFF / 64, NEXP), 256, 0, stream>>>(
      W2, W2t, DFF, DMODEL);
  for (int e0 = 0; e0 < NEXP; e0 += EC) {
    int ne = (NEXP - e0 < EC) ? (NEXP - e0) : EC;
    int nblk1 = 128 * ne;
    gemm1_kernel<<<nblk1, 512, 0, stream>>>(xb, W1t, b1, IDX, hbuf, e0, nblk1);
    int nblk2 = 32 * ne;
    gemm2_kernel<<<nblk2, 512, 0, stream>>>(hbuf, W2t, b2, G, Xe, e0, nblk2);
  }
  combine_kernel<<<NTOK / 4, 256, 0, stream>>>(Xe, inv, cnt, out);
}

// Round 11
// 412.118 us; speedup vs baseline: 1.2623x; 1.0018x over previous
//
#include <hip/hip_runtime.h>
#include <hip/hip_bf16.h>
#include <cstdint>
#include <cstddef>

#define NTOK 8192
#define DMODEL 1024
#define DFF 4096
#define NEXP 8
#define CAP 2048

typedef __attribute__((ext_vector_type(8))) __bf16 bf16x8;
typedef __attribute__((ext_vector_type(4))) float f32x4;

__device__ __forceinline__ void gload16(const void* g, void* l) {
  __builtin_amdgcn_global_load_lds(
      (__attribute__((address_space(1))) void*)(g),
      (__attribute__((address_space(3))) void*)(l),
      16, 0, 0);
}
#define VMWAIT_(n) asm volatile("s_waitcnt vmcnt(" #n ")" ::: "memory")
#define VMWAIT(n) VMWAIT_(n)
#define MEMFENCE asm volatile("" ::: "memory")

// Router: softmax scores + x->bf16; also zeroes cnt[] (consumed by topk's
// fused inverse-CSR scatter in the NEXT kernel — stream order guarantees).
__global__ __launch_bounds__(256) void router_kernel(
    const float* __restrict__ x, const float* __restrict__ Wr,
    float* __restrict__ scoresT, __hip_bfloat16* __restrict__ xb,
    int* __restrict__ cnt) {
  const int lane = threadIdx.x & 63;
  const int t = blockIdx.x * 4 + (threadIdx.x >> 6);
  if (lane == 0) cnt[t] = 0;
  const float* xr = x + (size_t)t * DMODEL;
  float acc[NEXP];
#pragma unroll
  for (int j = 0; j < NEXP; ++j) acc[j] = 0.f;
#pragma unroll
  for (int it = 0; it < DMODEL / 64; ++it) {
    int d = it * 64 + lane;
    float xv = xr[d];
    xb[(size_t)t * DMODEL + d] = __float2bfloat16(xv);
    const float4* w = (const float4*)(Wr + (size_t)d * NEXP);
    float4 w0 = w[0], w1 = w[1];
    acc[0] += xv * w0.x; acc[1] += xv * w0.y; acc[2] += xv * w0.z; acc[3] += xv * w0.w;
    acc[4] += xv * w1.x; acc[5] += xv * w1.y; acc[6] += xv * w1.z; acc[7] += xv * w1.w;
  }
#pragma unroll
  for (int off = 32; off; off >>= 1) {
#pragma unroll
    for (int j = 0; j < NEXP; ++j) acc[j] += __shfl_xor(acc[j], off);
  }
  float m = acc[0];
#pragma unroll
  for (int j = 1; j < NEXP; ++j) m = fmaxf(m, acc[j]);
  float s = 0.f;
#pragma unroll
  for (int j = 0; j < NEXP; ++j) { acc[j] = expf(acc[j] - m); s += acc[j]; }
  float inv = 1.f / s;
  if (lane < NEXP) scoresT[(size_t)lane * NTOK + t] = acc[lane] * inv;
}

// Exact top-k (radix-256 select, parallel suffix scan) + fused inverse-CSR
// scatter (cnt/inv): cross-block atomics are device-scope, race-free.
__global__ __launch_bounds__(256) void topk_kernel(
    const float* __restrict__ scoresT, float* __restrict__ G,
    int* __restrict__ IDX, int* __restrict__ cnt, int* __restrict__ inv) {
  __shared__ uint32_t sb[NTOK];
  __shared__ uint32_t hist[256];
  __shared__ uint32_t sfx[256];
  __shared__ uint32_t s_prefix, s_rem;
  __shared__ uint32_t eq_list[256];
  __shared__ uint32_t eq_cnt, gt_cnt;
  const int e = blockIdx.x, tid = threadIdx.x;
  const float* se = scoresT + (size_t)e * NTOK;
  for (int i = tid; i < NTOK; i += 256) sb[i] = __float_as_uint(se[i]);
  if (tid == 0) { s_prefix = 0u; s_rem = CAP; eq_cnt = 0u; gt_cnt = 0u; }
  __syncthreads();
  for (int r = 0; r < 4; ++r) {
    const int shift = 24 - 8 * r;
    hist[tid] = 0u;
    __syncthreads();
    uint32_t pfx = s_prefix;
    for (int i = tid; i < NTOK; i += 256) {
      uint32_t b = sb[i];
      if (((b >> shift) >> 8) == pfx) atomicAdd(&hist[(b >> shift) & 255u], 1u);
    }
    __syncthreads();
    sfx[tid] = hist[tid];
    __syncthreads();
#pragma unroll
    for (int off = 1; off < 256; off <<= 1) {
      uint32_t v = sfx[tid] + ((tid + off < 256) ? sfx[tid + off] : 0u);
      __syncthreads();
      sfx[tid] = v;
      __syncthreads();
    }
    uint32_t rem = s_rem;
    if (sfx[tid] >= rem && (tid == 255 || sfx[tid + 1] < rem)) {
      s_prefix = (pfx << 8) | (uint32_t)tid;
      s_rem = rem - ((tid == 255) ? 0u : sfx[tid + 1]);
    }
    __syncthreads();
  }
  const uint32_t T = s_prefix, need = s_rem;
  for (int i = tid; i < NTOK; i += 256) {
    uint32_t b = sb[i];
    if (b > T) {
      uint32_t p = atomicAdd(&gt_cnt, 1u);
      int slot = e * CAP + (int)p;
      IDX[slot] = i;
      G[slot] = __uint_as_float(b);
      int c = atomicAdd(&cnt[i], 1);
      inv[i * 8 + c] = slot;
    } else if (b == T) {
      uint32_t c = atomicAdd(&eq_cnt, 1u);
      if (c < 256u) eq_list[c] = (uint32_t)i;
    }
  }
  __syncthreads();
  if (tid == 0) {
    uint32_t base = gt_cnt;
    uint32_t c = eq_cnt < 256u ? eq_cnt : 256u;
    for (uint32_t s = 0; s < need; ++s) {
      uint32_t mv = 0xFFFFFFFFu; int mi = 0;
      for (uint32_t j = 0; j < c; ++j)
        if (eq_list[j] < mv) { mv = eq_list[j]; mi = (int)j; }
      eq_list[mi] = 0xFFFFFFFFu;
      int slot = e * CAP + (int)(base + s);
      IDX[slot] = (int)mv;
      G[slot] = __uint_as_float(T);
      int cc = atomicAdd(&cnt[mv], 1);
      inv[mv * 8 + cc] = slot;
    }
  }
}

// Combine: out[t] = sum over contributions (already g-scaled bf16 rows of Xe).
__global__ __launch_bounds__(256) void combine_kernel(
    const __hip_bfloat16* __restrict__ Xe, const int* __restrict__ inv,
    const int* __restrict__ cnt, float* __restrict__ out) {
  const int w = (blockIdx.x * 256 + threadIdx.x) >> 6;  // token id
  const int lane = threadIdx.x & 63;
  const int c = cnt[w];
  float a[16];
#pragma unroll
  for (int i = 0; i < 16; ++i) a[i] = 0.f;
  for (int j = 0; j < c; ++j) {
    int s = inv[w * 8 + j];
    const bf16x8* p = (const bf16x8*)(Xe + (size_t)s * DMODEL + lane * 16);
    bf16x8 v0 = p[0], v1 = p[1];
#pragma unroll
    for (int i = 0; i < 8; ++i) {
      a[i] += (float)v0[i];
      a[8 + i] += (float)v1[i];
    }
  }
  float4* o = (float4*)(out + (size_t)w * DMODEL + lane * 16);
#pragma unroll
  for (int q = 0; q < 4; ++q)
    o[q] = make_float4(a[q * 4], a[q * 4 + 1], a[q * 4 + 2], a[q * 4 + 3]);
}

// Both weight transposes (fp32 [E][R][C] -> bf16 [E][C][R]) in ONE launch.
// b < 8192: W1 (R=DMODEL,C=DFF); else W2 (R=DFF,C=DMODEL). 64x64 tiles.
__global__ __launch_bounds__(256) void transpose_cvt2(
    const float* __restrict__ W1, __hip_bfloat16* __restrict__ W1t,
    const float* __restrict__ W2, __hip_bfloat16* __restrict__ W2t) {
  __shared__ float tile[64][68];
  int b = blockIdx.x;
  const float* in; __hip_bfloat16* out; int R, C, bx, by, e;
  if (b < 8192) {
    in = W1; out = W1t; R = DMODEL; C = DFF;
    e = b >> 10; int t = b & 1023; bx = t & 63; by = t >> 6;      // 64 x 16
  } else {
    b -= 8192;
    in = W2; out = W2t; R = DFF; C = DMODEL;
    e = b >> 10; int t = b & 1023; bx = t & 15; by = t >> 4;      // 16 x 64
  }
  const float* ine = in + (size_t)e * R * C;
  __hip_bfloat16* oute = out + (size_t)e * R * C;
  const int c0 = bx * 64, r0 = by * 64;
  const int tid = threadIdx.x;
  const int lr = tid >> 4, lc = tid & 15;
#pragma unroll
  for (int it = 0; it < 4; ++it) {
    int row = it * 16 + lr;
    float4 v = *(const float4*)(ine + (size_t)(r0 + row) * C + c0 + lc * 4);
    *(float4*)&tile[row][lc * 4] = v;
  }
  __syncthreads();
  const int cc = tid >> 2, rq = tid & 3;
  unsigned short pk[16];
#pragma unroll
  for (int i = 0; i < 16; ++i) {
    __hip_bfloat16 bb = __float2bfloat16(tile[rq * 16 + i][cc]);
    pk[i] = *(unsigned short*)&bb;
  }
  char* dst = (char*)(oute + (size_t)(c0 + cc) * R + r0 + rq * 16);
  *(uint4*)dst = *(uint4*)&pk[0];
  *(uint4*)(dst + 16) = *(uint4*)&pk[8];
}

// ===== 256x256, BK=64, 8-phase / 2-K-tile pipeline (unchanged core) ========
#define RD_A(BASE, H)                                                          \
  {                                                                            \
    _Pragma("unroll") for (int mi = 0; mi < 4; ++mi)                           \
        _Pragma("unroll") for (int ks = 0; ks < 2; ++ks) av[mi][ks] =          \
        *(const bf16x8*)((BASE) + Ab + offA[(H)*4 + mi][ks]);                  \
  }
#define RD_B(BASE, BV, H2)                                                     \
  {                                                                            \
    _Pragma("unroll") for (int ni = 0; ni < 2; ++ni)                           \
        _Pragma("unroll") for (int ks = 0; ks < 2; ++ks) BV[ni][ks] =          \
        *(const bf16x8*)((BASE) + Bb + offB[(H2)*2 + ni][ks]);                 \
  }
#define STAGE_A(H, BUF)                                                        \
  {                                                                            \
    gload16(pa[(H)*2], (BUF) + (H)*16384 + dst);                               \
    pa[(H)*2] += 128;                                                          \
    gload16(pa[(H)*2 + 1], (BUF) + (H)*16384 + 8192 + dst);                    \
    pa[(H)*2 + 1] += 128;                                                      \
  }
#define STAGE_B(H, BUF)                                                        \
  {                                                                            \
    gload16(pb[(H)*2], (BUF) + 32768 + (H)*16384 + dst);                       \
    pb[(H)*2] += 128;                                                          \
    gload16(pb[(H)*2 + 1], (BUF) + 32768 + (H)*16384 + 8192 + dst);            \
    pb[(H)*2 + 1] += 128;                                                      \
  }
#define PH_PRE                                                                 \
  __builtin_amdgcn_s_barrier();                                                \
  MEMFENCE;                                                                    \
  __builtin_amdgcn_s_setprio(1);
#define PH_POST __builtin_amdgcn_s_setprio(0);
#define MFMA_Q(MB, NB, BV)                                                     \
  {                                                                            \
    _Pragma("unroll") for (int mi = 0; mi < 4; ++mi)                           \
        _Pragma("unroll") for (int ni = 0; ni < 2; ++ni)                       \
            _Pragma("unroll") for (int ks = 0; ks < 2; ++ks)                   \
                acc[(MB) + mi][(NB) + ni] =                                    \
        __builtin_amdgcn_mfma_f32_16x16x32_bf16(                               \
            av[mi][ks], BV[ni][ks], acc[(MB) + mi][(NB) + ni], 0, 0, 0);       \
  }

template <int NKT>
__device__ __forceinline__ void gemm_core8(
    const char* pa0, const char* pa1, const char* pa2, const char* pa3,
    const char* pb0, const char* pb1, const char* pb2, const char* pb3,
    char* smem, f32x4 (&acc)[8][4]) {
  const int tid = threadIdx.x;
  const int wave = tid >> 6, lane = tid & 63;
  const int wm = wave >> 2, wn = wave & 3;
  const int lrow = lane & 15, lgrp = lane >> 4;
  const int dst = tid * 16;

  const char* pa[4] = {pa0, pa1, pa2, pa3};
  const char* pb[4] = {pb0, pb1, pb2, pb3};

  int offA[8][2], offB[4][2];
#pragma unroll
  for (int mi = 0; mi < 8; ++mi) {
    int rL = mi * 16 + lrow;
#pragma unroll
    for (int ks = 0; ks < 2; ++ks)
      offA[mi][ks] = rL * 128 + ((((ks * 4 + lgrp) + rL) & 7) << 4);
  }
#pragma unroll
  for (int ni = 0; ni < 4; ++ni) {
    int rL = (wn & 1) * 64 + ni * 16 + lrow;
#pragma unroll
    for (int ks = 0; ks < 2; ++ks)
      offB[ni][ks] = rL * 128 + ((((ks * 4 + lgrp) + rL) & 7) << 4);
  }
  const int Ab = wm * 16384;
  const int Bb = 32768 + (wn >> 1) * 16384;

  char* b0 = smem;
  char* b1 = smem + 65536;

#pragma unroll
  for (int g = 0; g < 4; ++g) {
    gload16(pa[g], b0 + (g >> 1) * 16384 + (g & 1) * 8192 + dst);
    pa[g] += 128;
  }
#pragma unroll
  for (int g = 0; g < 4; ++g) {
    gload16(pb[g], b0 + 32768 + (g >> 1) * 16384 + (g & 1) * 8192 + dst);
    pb[g] += 128;
  }
#pragma unroll
  for (int g = 0; g < 4; ++g) {
    gload16(pb[g], b1 + 32768 + (g >> 1) * 16384 + (g & 1) * 8192 + dst);
    pb[g] += 128;
  }
  VMWAIT(4);
  __builtin_amdgcn_s_barrier();
  MEMFENCE;

  bf16x8 av[4][2], bv0[2][2], bv1[2][2];

  for (int i = 0; i < NKT / 2; ++i) {
    const bool st2 = (2 * i + 2 < NKT);
    const bool st3 = (2 * i + 3 < NKT);

    RD_A(b0, 0); RD_B(b0, bv0, 0);
    STAGE_A(0, b1);
    PH_PRE; MFMA_Q(0, 0, bv0); PH_POST;

    RD_B(b0, bv1, 1);
    STAGE_A(1, b1);
    PH_PRE; MFMA_Q(0, 2, bv1); PH_POST;

    RD_A(b0, 1);
    if (st2) STAGE_B(0, b0);
    PH_PRE; MFMA_Q(4, 2, bv1); PH_POST;

    if (st2) STAGE_B(1, b0);
    PH_PRE; MFMA_Q(4, 0, bv0);
    __builtin_amdgcn_s_setprio(0);
    if (st2) { VMWAIT(4); } else { VMWAIT(0); }
    __builtin_amdgcn_s_barrier();
    MEMFENCE;

    RD_A(b1, 0); RD_B(b1, bv0, 0);
    if (st2) STAGE_A(0, b0);
    PH_PRE; MFMA_Q(0, 0, bv0); PH_POST;

    RD_B(b1, bv1, 1);
    if (st2) STAGE_A(1, b0);
    PH_PRE; MFMA_Q(0, 2, bv1); PH_POST;

    RD_A(b1, 1);
    if (st3) STAGE_B(0, b1);
    PH_PRE; MFMA_Q(4, 2, bv1); PH_POST;

    if (st3) STAGE_B(1, b1);
    PH_PRE; MFMA_Q(4, 0, bv0);
    __builtin_amdgcn_s_setprio(0);
    if (st3) { VMWAIT(4); }
    __builtin_amdgcn_s_barrier();
    MEMFENCE;
  }
}

__device__ __forceinline__ float gelu_tanh(float v) {
  float t = 0.7978845608028654f * (v + 0.044715f * v * v * v);
  float e = __expf(2.f * t);
  float th = 1.f - 2.f / (e + 1.f);
  return 0.5f * v * (1.f + th);
}

__global__ __launch_bounds__(512, 2) void gemm1_kernel(
    const __hip_bfloat16* __restrict__ xb,
    const __hip_bfloat16* __restrict__ W1t,
    const float* __restrict__ b1,
    const int* __restrict__ IDX,
    __hip_bfloat16* __restrict__ h, int e0, int ne) {
  __shared__ __align__(16) char smem[131072];
  // expert<->XCD mapping: ez fastest (= XCD id when ne==8), then tm, then tn.
  int s = blockIdx.x;
  const int ez = s % ne;
  int r = s / ne;
  const int tm = r & 7, tn = r >> 3;
  const int e = e0 + ez;
  const int tid = threadIdx.x, wave = tid >> 6, lane = tid & 63;
  const int wm = wave >> 2, wn = wave & 3;
  const int lrow = lane & 15, lgrp = lane >> 4;

  const int r0 = tid >> 3;
  const int ksrc = (((tid & 7) - r0) & 7) * 16;
  const char* pa[4]; const char* pb[4];
#pragma unroll
  for (int g = 0; g < 4; ++g) {
    int m = g * 64 + r0;
    int tok = IDX[e * CAP + tm * 256 + m];
    pa[g] = (const char*)(xb + (size_t)tok * DMODEL) + ksrc;
    int n = g * 64 + r0;
    pb[g] = (const char*)(W1t + ((size_t)e * DFF + tn * 256 + n) * DMODEL) + ksrc;
  }

  f32x4 acc[8][4];
  f32x4 zero = {0.f, 0.f, 0.f, 0.f};
#pragma unroll
  for (int mi = 0; mi < 8; ++mi)
#pragma unroll
    for (int ni = 0; ni < 4; ++ni) acc[mi][ni] = zero;

  gemm_core8<DMODEL / 64>(pa[0], pa[1], pa[2], pa[3],
                          pb[0], pb[1], pb[2], pb[3], smem, acc);

  __hip_bfloat16* he = h + (size_t)ez * CAP * DFF;
  const float* b1e = b1 + (size_t)e * DFF;
  float bvals[4];
#pragma unroll
  for (int ni = 0; ni < 4; ++ni)
    bvals[ni] = b1e[tn * 256 + wn * 64 + ni * 16 + lrow];
  char* sb = smem;
  const int wswz = lgrp << 5;
#pragma unroll
  for (int mi = 0; mi < 8; ++mi) {
#pragma unroll
    for (int j = 0; j < 4; ++j) {
      int row = wm * 128 + mi * 16 + lgrp * 4 + j;
#pragma unroll
      for (int ni = 0; ni < 4; ++ni) {
        int col = wn * 64 + ni * 16 + lrow;
        float v = acc[mi][ni][j] + bvals[ni];
        v = gelu_tanh(v);
        *(__hip_bfloat16*)(sb + ((row * 512 + col * 2) ^ wswz)) =
            __float2bfloat16(v);
      }
    }
  }
  __syncthreads();
  size_t obase = (size_t)(tm * 256) * DFF + tn * 256;
#pragma unroll
  for (int c = 0; c < 16; ++c) {
    int byte = c * 8192 + tid * 16;
    int row = byte >> 9;
    int rswz = ((row >> 2) & 3) << 5;
    bf16x8 vals = *(const bf16x8*)(sb + (byte ^ rswz));
    int col = (byte & 511) >> 1;
    *(bf16x8*)(he + obase + (size_t)row * DFF + col) = vals;
  }
}

__global__ __launch_bounds__(512, 2) void gemm2_kernel(
    const __hip_bfloat16* __restrict__ h,
    const __hip_bfloat16* __restrict__ W2t,
    const float* __restrict__ b2,
    const float* __restrict__ G,
    __hip_bfloat16* __restrict__ Xe, int e0, int ne) {
  __shared__ __align__(16) char smem[131072];
  int s = blockIdx.x;
  const int ez = s % ne;
  int r = s / ne;
  const int tm = r & 7, tn = r >> 3;
  const int e = e0 + ez;
  const int tid = threadIdx.x, wave = tid >> 6, lane = tid & 63;
  const int wm = wave >> 2, wn = wave & 3;
  const int lrow = lane & 15, lgrp = lane >> 4;

  const int r0 = tid >> 3;
  const int ksrc = (((tid & 7) - r0) & 7) * 16;
  const char* pa[4]; const char* pb[4];
#pragma unroll
  for (int g = 0; g < 4; ++g) {
    int m = g * 64 + r0;
    pa[g] = (const char*)(h + ((size_t)ez * CAP + tm * 256 + m) * DFF) + ksrc;
    int n = g * 64 + r0;
    pb[g] = (const char*)(W2t + ((size_t)e * DMODEL + tn * 256 + n) * DFF) + ksrc;
  }

  f32x4 acc[8][4];
  f32x4 zero = {0.f, 0.f, 0.f, 0.f};
#pragma unroll
  for (int mi = 0; mi < 8; ++mi)
#pragma unroll
    for (int ni = 0; ni < 4; ++ni) acc[mi][ni] = zero;

  gemm_core8<DFF / 64>(pa[0], pa[1], pa[2], pa[3],
                       pb[0], pb[1], pb[2], pb[3], smem, acc);

  const float* b2e = b2 + (size_t)e * DMODEL;
  const float* ge = G + (size_t)e * CAP + tm * 256;
  float bvals[4];
#pragma unroll
  for (int ni = 0; ni < 4; ++ni)
    bvals[ni] = b2e[tn * 256 + wn * 64 + ni * 16 + lrow];
  char* sb = smem;
  const int wswz = lgrp << 5;
#pragma unroll
  for (int mi = 0; mi < 8; ++mi) {
#pragma unroll
    for (int j = 0; j < 4; ++j) {
      int row = wm * 128 + mi * 16 + lgrp * 4 + j;
      float g = ge[row];
#pragma unroll
      for (int ni = 0; ni < 4; ++ni) {
        int col = wn * 64 + ni * 16 + lrow;
        float v = (acc[mi][ni][j] + bvals[ni]) * g;
        *(__hip_bfloat16*)(sb + ((row * 512 + col * 2) ^ wswz)) =
            __float2bfloat16(v);
      }
    }
  }
  __syncthreads();
  __hip_bfloat16* xbase = Xe + ((size_t)(e * CAP + tm * 256)) * DMODEL + tn * 256;
#pragma unroll
  for (int c = 0; c < 16; ++c) {
    int byte = c * 8192 + tid * 16;
    int row = byte >> 9;
    int rswz = ((row >> 2) & 3) << 5;
    bf16x8 vals = *(const bf16x8*)(sb + (byte ^ rswz));
    int col = (byte & 511) >> 1;
    *(bf16x8*)(xbase + (size_t)row * DMODEL + col) = vals;
  }
}

extern "C" void kernel_launch(void* const* d_in, const int* in_sizes, int n_in,
                              void* d_out, int out_size, void* d_ws, size_t ws_size,
                              hipStream_t stream) {
  const float* x  = (const float*)d_in[0];
  const float* Wr = (const float*)d_in[1];
  const float* W1 = (const float*)d_in[2];
  const float* b1 = (const float*)d_in[3];
  const float* W2 = (const float*)d_in[4];
  const float* b2 = (const float*)d_in[5];
  float* out = (float*)d_out;
  char* ws = (char*)d_ws;

  size_t off = 0;
  float* scoresT = (float*)(ws + off); off += (size_t)NEXP * NTOK * 4;
  float* G       = (float*)(ws + off); off += (size_t)NEXP * CAP * 4;
  int*   IDX     = (int*)(ws + off);   off += (size_t)NEXP * CAP * 4;
  int*   cnt     = (int*)(ws + off);   off += (size_t)NTOK * 4;
  int*   inv     = (int*)(ws + off);   off += (size_t)NTOK * 8 * 4;
  __hip_bfloat16* xb  = (__hip_bfloat16*)(ws + off); off += (size_t)NTOK * DMODEL * 2;
  __hip_bfloat16* W1t = (__hip_bfloat16*)(ws + off); off += (size_t)NEXP * DFF * DMODEL * 2;
  __hip_bfloat16* W2t = (__hip_bfloat16*)(ws + off); off += (size_t)NEXP * DMODEL * DFF * 2;
  __hip_bfloat16* Xe  = (__hip_bfloat16*)(ws + off); off += (size_t)NEXP * CAP * DMODEL * 2;
  __hip_bfloat16* hbuf = (__hip_bfloat16*)(ws + off);
  size_t h_per_e = (size_t)CAP * DFF * 2;
  size_t avail = (ws_size > off) ? (ws_size - off) : 0;
  int EC = (int)(avail / h_per_e);
  if (EC < 1) EC = 1;
  if (EC > NEXP) EC = NEXP;

  router_kernel<<<NTOK / 4, 256, 0, stream>>>(x, Wr, scoresT, xb, cnt);
  topk_kernel<<<NEXP, 256, 0, stream>>>(scoresT, G, IDX, cnt, inv);
  transpose_cvt2<<<16384, 256, 0, stream>>>(W1, W1t, W2, W2t);
  for (int e0 = 0; e0 < NEXP; e0 += EC) {
    int ne = (NEXP - e0 < EC) ? (NEXP - e0) : EC;
    gemm1_kernel<<<128 * ne, 512, 0, stream>>>(xb, W1t, b1, IDX, hbuf, e0, ne);
    gemm2_kernel<<<32 * ne, 512, 0, stream>>>(hbuf, W2t, b2, G, Xe, e0, ne);
  }
  combine_kernel<<<NTOK / 4, 256, 0, stream>>>(Xe, inv, cnt, out);
}